// Round 1
// baseline (1351.063 us; speedup 1.0000x reference)
//
#include <hip/hip_runtime.h>
#include <math.h>

#define NN 50000
#define NE 800000
#define ET 850000   // NE + NN self loops
#define HCC 256     // H*C
#define GG 256

// ---------------- workspace layout (float-element offsets) ----------------
constexpr size_t NHC    = (size_t)NN * HCC;          // 12,800,000
constexpr size_t O_H    = 0;
constexpr size_t O_AGG  = O_H + NHC;
constexpr size_t O_XC   = O_AGG + NHC;
constexpr size_t O_AE   = O_XC + NHC;                // alphaE [ET,4]
constexpr size_t O_EID  = O_AE + (size_t)ET * 4;     // int
constexpr size_t O_START= O_EID + ET;                // int
constexpr size_t O_CUR  = O_START + NN;              // int
constexpr size_t O_AS   = O_CUR + NN;                // [NN,4]
constexpr size_t O_AD   = O_AS + (size_t)NN * 4;     // [NN,4]
constexpr size_t O_M    = O_AD + (size_t)NN * 4;     // [16,4]
constexpr size_t O_KV   = O_M + 64;                  // 256
constexpr size_t O_CV   = O_KV + 256;                // 256
// ---- zero zone (single memset) ----
constexpr size_t O_ZERO = O_CV + 256;
constexpr size_t O_DEG  = O_ZERO;                    // int [NN]
constexpr size_t O_CNT  = O_DEG + NN;                // int [GG]
constexpr size_t O_CTR  = O_CNT + GG;                // int [1] (+3 pad)
constexpr size_t O_MEAN = O_CTR + 4;                 // [16]
constexpr size_t O_SUM  = O_MEAN + 16;               // [3*256]
constexpr size_t O_SSQ  = O_SUM + 768;               // [3*256]
constexpr size_t O_POOL = O_SSQ + 768;               // [GG*HCC]
constexpr size_t O_END  = O_POOL + (size_t)GG * HCC;

// ---------------- CSR build ----------------
__global__ void deg_kernel(const int* __restrict__ dstA, int* __restrict__ deg) {
    int e = blockIdx.x * 256 + threadIdx.x;
    if (e >= ET) return;
    int d = (e < NE) ? dstA[e] : (e - NE);
    atomicAdd(&deg[d], 1);
}

__global__ void start_kernel(const int* __restrict__ deg, int* __restrict__ startA,
                             int* __restrict__ cur, int* __restrict__ ctr) {
    int n = blockIdx.x * 256 + threadIdx.x;
    if (n >= NN) return;
    int v = deg[n];
    int s = atomicAdd(ctr, v);
    startA[n] = s;
    cur[n] = s;
}

__global__ void scatter_kernel(const int* __restrict__ dstA, int* __restrict__ cur,
                               int* __restrict__ eid) {
    int e = blockIdx.x * 256 + threadIdx.x;
    if (e >= ET) return;
    int d = (e < NE) ? dstA[e] : (e - NE);
    int p = atomicAdd(&cur[d], 1);
    eid[p] = e;
}

// ---------------- edge-attention precompute ----------------
// M[k][h] = sum_c We0[k, h*64+c] * att_e0[h, c]
__global__ void m_kernel(const float* __restrict__ We0, const float* __restrict__ att_e0,
                         float* __restrict__ M) {
    int t = threadIdx.x;           // 64 threads
    int k = t >> 2, hh = t & 3;
    float s = 0.f;
    for (int c = 0; c < 64; ++c)
        s += We0[k * 256 + hh * 64 + c] * att_e0[hh * 64 + c];
    M[k * 4 + hh] = s;
}

// column sums of edge_attr [NE,16] -> meanacc (atomic)
__global__ void mean_kernel(const float* __restrict__ ea, float* __restrict__ meanacc) {
    __shared__ float part[256];
    int col = threadIdx.x & 15, rl = threadIdx.x >> 4;
    float s = 0.f;
    for (size_t r = (size_t)blockIdx.x * 16 + rl; r < NE; r += (size_t)gridDim.x * 16)
        s += ea[r * 16 + col];
    part[threadIdx.x] = s;
    __syncthreads();
    if (threadIdx.x < 16) {
        float t = 0.f;
        for (int j = 0; j < 16; ++j) t += part[threadIdx.x + j * 16];
        atomicAdd(&meanacc[threadIdx.x], t);
    }
}

__global__ void alphae_kernel(const float* __restrict__ ea, const float* __restrict__ M,
                              const float* __restrict__ meanacc, float* __restrict__ aE) {
    size_t e = (size_t)blockIdx.x * 256 + threadIdx.x;
    if (e >= ET) return;
    float v[16];
    if (e < NE) {
        const float4* p = (const float4*)(ea + e * 16);
        float4 a = p[0], b = p[1], c = p[2], d = p[3];
        v[0]=a.x; v[1]=a.y; v[2]=a.z; v[3]=a.w;
        v[4]=b.x; v[5]=b.y; v[6]=b.z; v[7]=b.w;
        v[8]=c.x; v[9]=c.y; v[10]=c.z; v[11]=c.w;
        v[12]=d.x; v[13]=d.y; v[14]=d.z; v[15]=d.w;
    } else {
        const float inv = 1.0f / (float)NE;
        #pragma unroll
        for (int k = 0; k < 16; ++k) v[k] = meanacc[k] * inv;
    }
    float o[4] = {0.f, 0.f, 0.f, 0.f};
    #pragma unroll
    for (int k = 0; k < 16; ++k) {
        float4 m4 = *(const float4*)(M + k * 4);
        o[0] = fmaf(v[k], m4.x, o[0]);
        o[1] = fmaf(v[k], m4.y, o[1]);
        o[2] = fmaf(v[k], m4.z, o[2]);
        o[3] = fmaf(v[k], m4.w, o[3]);
    }
    *(float4*)(aE + e * 4) = make_float4(o[0], o[1], o[2], o[3]);
}

// ---------------- GEMM: h = A[M,K] @ B[K,256] ----------------
template <int K>
__global__ __launch_bounds__(256) void gemm_kernel(const float* __restrict__ A,
                                                   const float* __restrict__ B,
                                                   float* __restrict__ Hout, int M) {
    __shared__ float As[16][68];   // [k][row], padded for 16B-aligned b128 reads
    __shared__ float Bs[16][64];   // [k][col]
    int tid = threadIdx.x;
    int row0 = blockIdx.x * 64;
    int col0 = blockIdx.y * 64;
    int tx = tid & 15, ty = tid >> 4;
    int arow = tid >> 2, ak = (tid & 3) * 4;
    float acc[4][4] = {};
    for (int kt = 0; kt < K; kt += 16) {
        float4 av = make_float4(0.f, 0.f, 0.f, 0.f);
        if (row0 + arow < M)
            av = *(const float4*)(A + (size_t)(row0 + arow) * K + kt + ak);
        As[ak + 0][arow] = av.x;
        As[ak + 1][arow] = av.y;
        As[ak + 2][arow] = av.z;
        As[ak + 3][arow] = av.w;
        float4 bv = *(const float4*)(B + (size_t)(kt + ty) * HCC + col0 + tx * 4);
        *(float4*)&Bs[ty][tx * 4] = bv;
        __syncthreads();
        #pragma unroll
        for (int kk = 0; kk < 16; ++kk) {
            float4 a = *(const float4*)&As[kk][ty * 4];
            float4 b = *(const float4*)&Bs[kk][tx * 4];
            acc[0][0] = fmaf(a.x, b.x, acc[0][0]);
            acc[0][1] = fmaf(a.x, b.y, acc[0][1]);
            acc[0][2] = fmaf(a.x, b.z, acc[0][2]);
            acc[0][3] = fmaf(a.x, b.w, acc[0][3]);
            acc[1][0] = fmaf(a.y, b.x, acc[1][0]);
            acc[1][1] = fmaf(a.y, b.y, acc[1][1]);
            acc[1][2] = fmaf(a.y, b.z, acc[1][2]);
            acc[1][3] = fmaf(a.y, b.w, acc[1][3]);
            acc[2][0] = fmaf(a.z, b.x, acc[2][0]);
            acc[2][1] = fmaf(a.z, b.y, acc[2][1]);
            acc[2][2] = fmaf(a.z, b.z, acc[2][2]);
            acc[2][3] = fmaf(a.z, b.w, acc[2][3]);
            acc[3][0] = fmaf(a.w, b.x, acc[3][0]);
            acc[3][1] = fmaf(a.w, b.y, acc[3][1]);
            acc[3][2] = fmaf(a.w, b.z, acc[3][2]);
            acc[3][3] = fmaf(a.w, b.w, acc[3][3]);
        }
        __syncthreads();
    }
    #pragma unroll
    for (int i = 0; i < 4; ++i) {
        int r = row0 + ty * 4 + i;
        if (r < M) {
            float4 o = make_float4(acc[i][0], acc[i][1], acc[i][2], acc[i][3]);
            *(float4*)(Hout + (size_t)r * HCC + col0 + tx * 4) = o;
        }
    }
}

// ---------------- per-node attention logits ----------------
__global__ void asad_kernel(const float* __restrict__ Hm, const float* __restrict__ att_src,
                            const float* __restrict__ att_dst, float* __restrict__ asA,
                            float* __restrict__ adA) {
    int wave = threadIdx.x >> 6, lane = threadIdx.x & 63;
    int n = blockIdx.x * 4 + wave;
    if (n >= NN) return;
    int head = lane >> 4;
    int ci = (lane & 15) * 4;
    float4 hv = *(const float4*)(Hm + (size_t)n * HCC + lane * 4);
    float4 s4 = *(const float4*)(att_src + head * 64 + ci);
    float4 d4 = *(const float4*)(att_dst + head * 64 + ci);
    float ps = hv.x * s4.x + hv.y * s4.y + hv.z * s4.z + hv.w * s4.w;
    float pd = hv.x * d4.x + hv.y * d4.y + hv.z * d4.z + hv.w * d4.w;
    #pragma unroll
    for (int off = 8; off; off >>= 1) {
        ps += __shfl_xor(ps, off);
        pd += __shfl_xor(pd, off);
    }
    if ((lane & 15) == 0) {
        asA[n * 4 + head] = ps;
        adA[n * 4 + head] = pd;
    }
}

// ---------------- per-node softmax aggregation (wave per node) ----------------
template <bool HAS_AE>
__global__ __launch_bounds__(256) void agg_kernel(const float* __restrict__ Hm,
                                                  const float* __restrict__ asA,
                                                  const float* __restrict__ adA,
                                                  const float* __restrict__ aE,
                                                  const int* __restrict__ eid,
                                                  const int* __restrict__ startA,
                                                  const int* __restrict__ degA,
                                                  const int* __restrict__ srcA,
                                                  float* __restrict__ outA) {
    int wave = threadIdx.x >> 6, lane = threadIdx.x & 63;
    int n = blockIdx.x * 4 + wave;
    if (n >= NN) return;
    int head = lane >> 4;
    int st = startA[n];
    int d = degA[n];
    float4 ad4 = *(const float4*)(adA + (size_t)n * 4);
    float adh = (head == 0) ? ad4.x : (head == 1) ? ad4.y : (head == 2) ? ad4.z : ad4.w;
    // pass 1: segment max (lanes parallel over edges)
    float mh[4] = {-1e30f, -1e30f, -1e30f, -1e30f};
    for (int j = lane; j < d; j += 64) {
        int e = eid[st + j];
        int s = (e < NE) ? srcA[e] : n;
        float4 a4 = *(const float4*)(asA + (size_t)s * 4);
        float a[4] = {a4.x + ad4.x, a4.y + ad4.y, a4.z + ad4.z, a4.w + ad4.w};
        if (HAS_AE) {
            float4 e4 = *(const float4*)(aE + (size_t)e * 4);
            a[0] += e4.x; a[1] += e4.y; a[2] += e4.z; a[3] += e4.w;
        }
        #pragma unroll
        for (int q = 0; q < 4; ++q) {
            float t = (a[q] > 0.f) ? a[q] : 0.2f * a[q];
            mh[q] = fmaxf(mh[q], t);
        }
    }
    #pragma unroll
    for (int q = 0; q < 4; ++q)
        for (int off = 32; off; off >>= 1)
            mh[q] = fmaxf(mh[q], __shfl_xor(mh[q], off));
    float mymax = (head == 0) ? mh[0] : (head == 1) ? mh[1] : (head == 2) ? mh[2] : mh[3];
    // pass 2: weighted accumulate (wave iterates edges, lanes = 4 channels each)
    float D = 0.f;
    float acc0 = 0.f, acc1 = 0.f, acc2 = 0.f, acc3 = 0.f;
    for (int j = 0; j < d; ++j) {
        int e = eid[st + j];
        int s = (e < NE) ? srcA[e] : n;
        float a = asA[(size_t)s * 4 + head] + adh;
        if (HAS_AE) a += aE[(size_t)e * 4 + head];
        a = (a > 0.f) ? a : 0.2f * a;
        float w = __expf(a - mymax);
        D += w;
        float4 hv = *(const float4*)(Hm + (size_t)s * HCC + lane * 4);
        acc0 = fmaf(w, hv.x, acc0);
        acc1 = fmaf(w, hv.y, acc1);
        acc2 = fmaf(w, hv.z, acc2);
        acc3 = fmaf(w, hv.w, acc3);
    }
    float inv = 1.0f / (D + 1e-16f);
    float4 o = make_float4(acc0 * inv, acc1 * inv, acc2 * inv, acc3 * inv);
    *(float4*)(outA + (size_t)n * HCC + lane * 4) = o;
}

// ---------------- BN stats ----------------
__global__ void stats_kernel(const float* __restrict__ agg, float* __restrict__ sum,
                             float* __restrict__ ssq) {
    int ch = threadIdx.x;
    float s = 0.f, s2 = 0.f;
    for (int r = blockIdx.x; r < NN; r += gridDim.x) {
        float v = agg[(size_t)r * HCC + ch];
        s += v;
        s2 = fmaf(v, v, s2);
    }
    atomicAdd(&sum[ch], s);
    atomicAdd(&ssq[ch], s2);
}

// bias cancels under batch-stat BN: normalized = (agg - mean_raw)*k + beta
__global__ void bnfin_kernel(const float* __restrict__ sum, const float* __restrict__ ssq,
                             const float* __restrict__ gamma, const float* __restrict__ beta,
                             float* __restrict__ kv, float* __restrict__ cv) {
    int ch = threadIdx.x;
    const float invN = 1.0f / (float)NN;
    float mr = sum[ch] * invN;
    float var = ssq[ch] * invN - mr * mr;
    float k = gamma[ch] * rsqrtf(var + 1e-5f);
    kv[ch] = k;
    cv[ch] = beta[ch] - mr * k;
}

__global__ void norm_kernel(const float* __restrict__ agg, const float* __restrict__ kv,
                            const float* __restrict__ cv, float* __restrict__ xo) {
    size_t idx = (size_t)blockIdx.x * 256 + threadIdx.x;
    size_t i = idx * 4;
    if (i >= NHC) return;
    int ch = (int)(i & 255);
    float4 v = *(const float4*)(agg + i);
    float4 k4 = *(const float4*)(kv + ch);
    float4 c4 = *(const float4*)(cv + ch);
    v.x = fmaxf(fmaf(v.x, k4.x, c4.x), 0.f);
    v.y = fmaxf(fmaf(v.y, k4.y, c4.y), 0.f);
    v.z = fmaxf(fmaf(v.z, k4.z, c4.z), 0.f);
    v.w = fmaxf(fmaf(v.w, k4.w, c4.w), 0.f);
    *(float4*)(xo + i) = v;
}

// ---------------- pooling (batch is sorted: run-length local accumulation) ----------------
__global__ void pool_kernel(const float* __restrict__ xf, const int* __restrict__ batch,
                            float* __restrict__ pool, int* __restrict__ cnt) {
    int ch = threadIdx.x;
    int nbase = blockIdx.x * 64;
    float acc = 0.f;
    int mc = 0;
    int curg = batch[nbase];
    for (int r = 0; r < 64; ++r) {
        int n = nbase + r;
        if (n >= NN) break;
        int g = batch[n];
        if (g != curg) {
            atomicAdd(&pool[(size_t)curg * HCC + ch], acc);
            if (ch == 0) atomicAdd(&cnt[curg], mc);
            acc = 0.f; mc = 0; curg = g;
        }
        acc += xf[(size_t)n * HCC + ch];
        mc++;
    }
    atomicAdd(&pool[(size_t)curg * HCC + ch], acc);
    if (ch == 0) atomicAdd(&cnt[curg], mc);
}

__global__ void final_kernel(const float* __restrict__ pool, const int* __restrict__ cnt,
                             float* __restrict__ out) {
    int idx = blockIdx.x * 256 + threadIdx.x;
    int g = idx >> 8;
    float c = fmaxf((float)cnt[g], 1.0f);
    out[idx] = pool[idx] / c;
}

// ---------------- launch ----------------
extern "C" void kernel_launch(void* const* d_in, const int* in_sizes, int n_in,
                              void* d_out, int out_size, void* d_ws, size_t ws_size,
                              hipStream_t stream) {
    const float* x = (const float*)d_in[0];
    const int* edge_index = (const int*)d_in[1];
    const int* srcA = edge_index;
    const int* dstA = edge_index + NE;
    const float* edge_attr = (const float*)d_in[2];
    const int* batch = (const int*)d_in[3];
    const float* W[3]   = {(const float*)d_in[4],  (const float*)d_in[10], (const float*)d_in[16]};
    const float* asc[3] = {(const float*)d_in[5],  (const float*)d_in[11], (const float*)d_in[17]};
    const float* adc[3] = {(const float*)d_in[6],  (const float*)d_in[12], (const float*)d_in[18]};
    const float* gam[3] = {(const float*)d_in[8],  (const float*)d_in[14], (const float*)d_in[20]};
    const float* bet[3] = {(const float*)d_in[9],  (const float*)d_in[15], (const float*)d_in[21]};
    const float* We0 = (const float*)d_in[22];
    const float* att_e0 = (const float*)d_in[23];

    float* wsf = (float*)d_ws;
    float* hbuf  = wsf + O_H;
    float* aggb  = wsf + O_AGG;
    float* xcur  = wsf + O_XC;
    float* aE    = wsf + O_AE;
    int*   eid   = (int*)(wsf + O_EID);
    int*   startA= (int*)(wsf + O_START);
    int*   cur   = (int*)(wsf + O_CUR);
    float* asA   = wsf + O_AS;
    float* adA   = wsf + O_AD;
    float* Mb    = wsf + O_M;
    float* kv    = wsf + O_KV;
    float* cv    = wsf + O_CV;
    int*   deg   = (int*)(wsf + O_DEG);
    int*   cnt   = (int*)(wsf + O_CNT);
    int*   ctr   = (int*)(wsf + O_CTR);
    float* meanacc = wsf + O_MEAN;
    float* sums  = wsf + O_SUM;
    float* ssqs  = wsf + O_SSQ;
    float* pool  = wsf + O_POOL;

    hipMemsetAsync((void*)(wsf + O_ZERO), 0, (O_END - O_ZERO) * sizeof(float), stream);

    // CSR over dst (shared by all layers)
    deg_kernel<<<(ET + 255) / 256, 256, 0, stream>>>(dstA, deg);
    start_kernel<<<(NN + 255) / 256, 256, 0, stream>>>(deg, startA, cur, ctr);
    scatter_kernel<<<(ET + 255) / 256, 256, 0, stream>>>(dstA, cur, eid);

    // edge attention logits (layer 0 only)
    m_kernel<<<1, 64, 0, stream>>>(We0, att_e0, Mb);
    mean_kernel<<<256, 256, 0, stream>>>(edge_attr, meanacc);
    alphae_kernel<<<(ET + 255) / 256, 256, 0, stream>>>(edge_attr, Mb, meanacc, aE);

    const float* xin = x;
    for (int L = 0; L < 3; ++L) {
        if (L == 0)
            gemm_kernel<128><<<dim3(782, 4), 256, 0, stream>>>(xin, W[L], hbuf, NN);
        else
            gemm_kernel<256><<<dim3(782, 4), 256, 0, stream>>>(xin, W[L], hbuf, NN);
        asad_kernel<<<12500, 256, 0, stream>>>(hbuf, asc[L], adc[L], asA, adA);
        if (L == 0)
            agg_kernel<true><<<12500, 256, 0, stream>>>(hbuf, asA, adA, aE, eid, startA, deg, srcA, aggb);
        else
            agg_kernel<false><<<12500, 256, 0, stream>>>(hbuf, asA, adA, aE, eid, startA, deg, srcA, aggb);
        stats_kernel<<<256, 256, 0, stream>>>(aggb, sums + L * 256, ssqs + L * 256);
        bnfin_kernel<<<1, 256, 0, stream>>>(sums + L * 256, ssqs + L * 256, gam[L], bet[L], kv, cv);
        norm_kernel<<<12500, 256, 0, stream>>>(aggb, kv, cv, xcur);
        xin = xcur;
    }

    pool_kernel<<<782, 256, 0, stream>>>(xcur, batch, pool, cnt);
    final_kernel<<<256, 256, 0, stream>>>(pool, cnt, (float*)d_out);
}

// Round 2
// 1231.503 us; speedup vs baseline: 1.0971x; 1.0971x over previous
//
#include <hip/hip_runtime.h>
#include <math.h>

#define NN 50000
#define NE 800000
#define ET 850000   // NE + NN self loops
#define HCC 256     // H*C
#define GG 256

// ---------------- workspace layout (float-element offsets) ----------------
constexpr size_t NHC    = (size_t)NN * HCC;          // 12,800,000
constexpr size_t O_H    = 0;
constexpr size_t O_AGG  = O_H + NHC;
constexpr size_t O_XC   = O_AGG + NHC;
constexpr size_t O_AE   = O_XC + NHC;                // alphaE [ET,4] (edge-indexed)
constexpr size_t O_EID  = O_AE + (size_t)ET * 4;     // int [ET] CSR pos -> edge id
constexpr size_t O_SRCP = O_EID + ET;                // int [ET] CSR pos -> src node
constexpr size_t O_DSTP = O_SRCP + ET;               // int [ET] CSR pos -> dst node
constexpr size_t O_ALP  = O_DSTP + ET;               // [ET,4] leaky logits, CSR order
constexpr size_t O_START= O_ALP + (size_t)ET * 4;    // int [NN]
constexpr size_t O_CUR  = O_START + NN;              // int [NN]
constexpr size_t O_AS   = O_CUR + NN;                // [NN,4]
constexpr size_t O_AD   = O_AS + (size_t)NN * 4;     // [NN,4]
constexpr size_t O_M    = O_AD + (size_t)NN * 4;     // [16,4]
constexpr size_t O_KV   = O_M + 64;                  // 256
constexpr size_t O_CV   = O_KV + 256;                // 256
// ---- zero zone (single memset) ----
constexpr size_t O_ZERO = O_CV + 256;
constexpr size_t O_DEG  = O_ZERO;                    // int [NN]
constexpr size_t O_CNT  = O_DEG + NN;                // int [GG]
constexpr size_t O_CTR  = O_CNT + GG;                // int [1] (+3 pad)
constexpr size_t O_MEAN = O_CTR + 4;                 // [16]
constexpr size_t O_SUM  = O_MEAN + 16;               // [3*256]
constexpr size_t O_SSQ  = O_SUM + 768;               // [3*256]
constexpr size_t O_POOL = O_SSQ + 768;               // [GG*HCC]
constexpr size_t O_END  = O_POOL + (size_t)GG * HCC;

__device__ inline float rlf(float v, int l) {
    return __int_as_float(__builtin_amdgcn_readlane(__float_as_int(v), l));
}

// ---------------- CSR build ----------------
__global__ void deg_kernel(const int* __restrict__ dstA, int* __restrict__ deg) {
    int e = blockIdx.x * 256 + threadIdx.x;
    if (e >= ET) return;
    int d = (e < NE) ? dstA[e] : (e - NE);
    atomicAdd(&deg[d], 1);
}

__global__ void start_kernel(const int* __restrict__ deg, int* __restrict__ startA,
                             int* __restrict__ cur, int* __restrict__ ctr) {
    int n = blockIdx.x * 256 + threadIdx.x;
    if (n >= NN) return;
    int v = deg[n];
    int s = atomicAdd(ctr, v);
    startA[n] = s;
    cur[n] = s;
}

__global__ void scatter_kernel(const int* __restrict__ srcA, const int* __restrict__ dstA,
                               int* __restrict__ cur, int* __restrict__ eid,
                               int* __restrict__ srcP, int* __restrict__ dstP) {
    int e = blockIdx.x * 256 + threadIdx.x;
    if (e >= ET) return;
    int d = (e < NE) ? dstA[e] : (e - NE);
    int s = (e < NE) ? srcA[e] : (e - NE);
    int p = atomicAdd(&cur[d], 1);
    eid[p] = e;
    srcP[p] = s;
    dstP[p] = d;
}

// ---------------- edge-attention precompute ----------------
// M[k][h] = sum_c We0[k, h*64+c] * att_e0[h, c]
__global__ void m_kernel(const float* __restrict__ We0, const float* __restrict__ att_e0,
                         float* __restrict__ M) {
    int t = threadIdx.x;           // 64 threads
    int k = t >> 2, hh = t & 3;
    float s = 0.f;
    for (int c = 0; c < 64; ++c)
        s += We0[k * 256 + hh * 64 + c] * att_e0[hh * 64 + c];
    M[k * 4 + hh] = s;
}

// column sums of edge_attr [NE,16] -> meanacc (atomic)
__global__ void mean_kernel(const float* __restrict__ ea, float* __restrict__ meanacc) {
    __shared__ float part[256];
    int col = threadIdx.x & 15, rl = threadIdx.x >> 4;
    float s = 0.f;
    for (size_t r = (size_t)blockIdx.x * 16 + rl; r < NE; r += (size_t)gridDim.x * 16)
        s += ea[r * 16 + col];
    part[threadIdx.x] = s;
    __syncthreads();
    if (threadIdx.x < 16) {
        float t = 0.f;
        for (int j = 0; j < 16; ++j) t += part[threadIdx.x + j * 16];
        atomicAdd(&meanacc[threadIdx.x], t);
    }
}

__global__ void alphae_kernel(const float* __restrict__ ea, const float* __restrict__ M,
                              const float* __restrict__ meanacc, float* __restrict__ aE) {
    size_t e = (size_t)blockIdx.x * 256 + threadIdx.x;
    if (e >= ET) return;
    float v[16];
    if (e < NE) {
        const float4* p = (const float4*)(ea + e * 16);
        float4 a = p[0], b = p[1], c = p[2], d = p[3];
        v[0]=a.x; v[1]=a.y; v[2]=a.z; v[3]=a.w;
        v[4]=b.x; v[5]=b.y; v[6]=b.z; v[7]=b.w;
        v[8]=c.x; v[9]=c.y; v[10]=c.z; v[11]=c.w;
        v[12]=d.x; v[13]=d.y; v[14]=d.z; v[15]=d.w;
    } else {
        const float inv = 1.0f / (float)NE;
        #pragma unroll
        for (int k = 0; k < 16; ++k) v[k] = meanacc[k] * inv;
    }
    float o[4] = {0.f, 0.f, 0.f, 0.f};
    #pragma unroll
    for (int k = 0; k < 16; ++k) {
        float4 m4 = *(const float4*)(M + k * 4);
        o[0] = fmaf(v[k], m4.x, o[0]);
        o[1] = fmaf(v[k], m4.y, o[1]);
        o[2] = fmaf(v[k], m4.z, o[2]);
        o[3] = fmaf(v[k], m4.w, o[3]);
    }
    *(float4*)(aE + e * 4) = make_float4(o[0], o[1], o[2], o[3]);
}

// ---------------- per-edge leaky logits in CSR order ----------------
template <bool HAS_AE>
__global__ void alphap_kernel(const int* __restrict__ srcP, const int* __restrict__ dstP,
                              const int* __restrict__ eid, const float* __restrict__ asA,
                              const float* __restrict__ adA, const float* __restrict__ aE,
                              float* __restrict__ alphaP) {
    size_t p = (size_t)blockIdx.x * 256 + threadIdx.x;
    if (p >= ET) return;
    int s = srcP[p], d = dstP[p];
    float4 av = *(const float4*)(asA + (size_t)s * 4);
    float4 dv = *(const float4*)(adA + (size_t)d * 4);
    float4 t = make_float4(av.x + dv.x, av.y + dv.y, av.z + dv.z, av.w + dv.w);
    if (HAS_AE) {
        int e = eid[p];
        float4 e4 = *(const float4*)(aE + (size_t)e * 4);
        t.x += e4.x; t.y += e4.y; t.z += e4.z; t.w += e4.w;
    }
    t.x = (t.x > 0.f) ? t.x : 0.2f * t.x;
    t.y = (t.y > 0.f) ? t.y : 0.2f * t.y;
    t.z = (t.z > 0.f) ? t.z : 0.2f * t.z;
    t.w = (t.w > 0.f) ? t.w : 0.2f * t.w;
    *(float4*)(alphaP + p * 4) = t;
}

// ---------------- GEMM: h = A[M,K] @ B[K,256] ----------------
template <int K>
__global__ __launch_bounds__(256) void gemm_kernel(const float* __restrict__ A,
                                                   const float* __restrict__ B,
                                                   float* __restrict__ Hout, int M) {
    __shared__ float As[16][68];   // [k][row], padded
    __shared__ float Bs[16][64];   // [k][col]
    int tid = threadIdx.x;
    int row0 = blockIdx.x * 64;
    int col0 = blockIdx.y * 64;
    int tx = tid & 15, ty = tid >> 4;
    int arow = tid >> 2, ak = (tid & 3) * 4;
    float acc[4][4] = {};
    for (int kt = 0; kt < K; kt += 16) {
        float4 av = make_float4(0.f, 0.f, 0.f, 0.f);
        if (row0 + arow < M)
            av = *(const float4*)(A + (size_t)(row0 + arow) * K + kt + ak);
        As[ak + 0][arow] = av.x;
        As[ak + 1][arow] = av.y;
        As[ak + 2][arow] = av.z;
        As[ak + 3][arow] = av.w;
        float4 bv = *(const float4*)(B + (size_t)(kt + ty) * HCC + col0 + tx * 4);
        *(float4*)&Bs[ty][tx * 4] = bv;
        __syncthreads();
        #pragma unroll
        for (int kk = 0; kk < 16; ++kk) {
            float4 a = *(const float4*)&As[kk][ty * 4];
            float4 b = *(const float4*)&Bs[kk][tx * 4];
            acc[0][0] = fmaf(a.x, b.x, acc[0][0]);
            acc[0][1] = fmaf(a.x, b.y, acc[0][1]);
            acc[0][2] = fmaf(a.x, b.z, acc[0][2]);
            acc[0][3] = fmaf(a.x, b.w, acc[0][3]);
            acc[1][0] = fmaf(a.y, b.x, acc[1][0]);
            acc[1][1] = fmaf(a.y, b.y, acc[1][1]);
            acc[1][2] = fmaf(a.y, b.z, acc[1][2]);
            acc[1][3] = fmaf(a.y, b.w, acc[1][3]);
            acc[2][0] = fmaf(a.z, b.x, acc[2][0]);
            acc[2][1] = fmaf(a.z, b.y, acc[2][1]);
            acc[2][2] = fmaf(a.z, b.z, acc[2][2]);
            acc[2][3] = fmaf(a.z, b.w, acc[2][3]);
            acc[3][0] = fmaf(a.w, b.x, acc[3][0]);
            acc[3][1] = fmaf(a.w, b.y, acc[3][1]);
            acc[3][2] = fmaf(a.w, b.z, acc[3][2]);
            acc[3][3] = fmaf(a.w, b.w, acc[3][3]);
        }
        __syncthreads();
    }
    #pragma unroll
    for (int i = 0; i < 4; ++i) {
        int r = row0 + ty * 4 + i;
        if (r < M) {
            float4 o = make_float4(acc[i][0], acc[i][1], acc[i][2], acc[i][3]);
            *(float4*)(Hout + (size_t)r * HCC + col0 + tx * 4) = o;
        }
    }
}

// ---------------- per-node attention logits ----------------
__global__ void asad_kernel(const float* __restrict__ Hm, const float* __restrict__ att_src,
                            const float* __restrict__ att_dst, float* __restrict__ asA,
                            float* __restrict__ adA) {
    int wave = threadIdx.x >> 6, lane = threadIdx.x & 63;
    int n = blockIdx.x * 4 + wave;
    if (n >= NN) return;
    int head = lane >> 4;
    int ci = (lane & 15) * 4;
    float4 hv = *(const float4*)(Hm + (size_t)n * HCC + lane * 4);
    float4 s4 = *(const float4*)(att_src + head * 64 + ci);
    float4 d4 = *(const float4*)(att_dst + head * 64 + ci);
    float ps = hv.x * s4.x + hv.y * s4.y + hv.z * s4.z + hv.w * s4.w;
    float pd = hv.x * d4.x + hv.y * d4.y + hv.z * d4.z + hv.w * d4.w;
    #pragma unroll
    for (int off = 8; off; off >>= 1) {
        ps += __shfl_xor(ps, off);
        pd += __shfl_xor(pd, off);
    }
    if ((lane & 15) == 0) {
        asA[n * 4 + head] = ps;
        adA[n * 4 + head] = pd;
    }
}

// ---------------- per-node softmax aggregation (wave per node, CSR-ordered) --
__global__ __launch_bounds__(256) void agg_kernel(const float* __restrict__ Hm,
                                                  const float* __restrict__ alphaP,
                                                  const int* __restrict__ srcP,
                                                  const int* __restrict__ startA,
                                                  const int* __restrict__ degA,
                                                  float* __restrict__ outA) {
    int wave = threadIdx.x >> 6, lane = threadIdx.x & 63;
    int n = blockIdx.x * 4 + wave;
    if (n >= NN) return;
    int head = lane >> 4;
    int st = startA[n];
    int d = degA[n];

    // pass 1: component-wise max over edges (lane j <-> edge j)
    float4 m4 = make_float4(-1e30f, -1e30f, -1e30f, -1e30f);
    for (int j = lane; j < d; j += 64) {
        float4 a = *(const float4*)(alphaP + (size_t)(st + j) * 4);
        m4.x = fmaxf(m4.x, a.x); m4.y = fmaxf(m4.y, a.y);
        m4.z = fmaxf(m4.z, a.z); m4.w = fmaxf(m4.w, a.w);
    }
    #pragma unroll
    for (int off = 32; off; off >>= 1) {
        m4.x = fmaxf(m4.x, __shfl_xor(m4.x, off));
        m4.y = fmaxf(m4.y, __shfl_xor(m4.y, off));
        m4.z = fmaxf(m4.z, __shfl_xor(m4.z, off));
        m4.w = fmaxf(m4.w, __shfl_xor(m4.w, off));
    }

    // pass 2: chunks of 64 edges; w held in registers, broadcast via readlane
    float4 Dv = make_float4(0.f, 0.f, 0.f, 0.f);
    float4 acc = make_float4(0.f, 0.f, 0.f, 0.f);
    const float* hb = Hm + lane * 4;
    for (int base = 0; base < d; base += 64) {
        int j = base + lane;
        float4 a4 = make_float4(-1e30f, -1e30f, -1e30f, -1e30f);
        int ms = 0;
        if (j < d) {
            a4 = *(const float4*)(alphaP + (size_t)(st + j) * 4);
            ms = srcP[st + j];
        }
        float4 w4;
        w4.x = __expf(a4.x - m4.x);   // 0 for out-of-range lanes
        w4.y = __expf(a4.y - m4.y);
        w4.z = __expf(a4.z - m4.z);
        w4.w = __expf(a4.w - m4.w);
        Dv.x += w4.x; Dv.y += w4.y; Dv.z += w4.z; Dv.w += w4.w;

        int cnt = d - base; if (cnt > 64) cnt = 64;
        int cnt4 = (cnt + 3) & ~3;    // padded lanes have w=0, safe
        for (int jj = 0; jj < cnt4; jj += 4) {
            int s0 = __builtin_amdgcn_readlane(ms, jj);
            int s1 = __builtin_amdgcn_readlane(ms, jj + 1);
            int s2 = __builtin_amdgcn_readlane(ms, jj + 2);
            int s3 = __builtin_amdgcn_readlane(ms, jj + 3);
            float4 h0 = *(const float4*)(hb + (size_t)s0 * HCC);
            float4 h1 = *(const float4*)(hb + (size_t)s1 * HCC);
            float4 h2 = *(const float4*)(hb + (size_t)s2 * HCC);
            float4 h3 = *(const float4*)(hb + (size_t)s3 * HCC);
            float w0x = rlf(w4.x, jj),     w0y = rlf(w4.y, jj),     w0z = rlf(w4.z, jj),     w0w = rlf(w4.w, jj);
            float w1x = rlf(w4.x, jj + 1), w1y = rlf(w4.y, jj + 1), w1z = rlf(w4.z, jj + 1), w1w = rlf(w4.w, jj + 1);
            float w2x = rlf(w4.x, jj + 2), w2y = rlf(w4.y, jj + 2), w2z = rlf(w4.z, jj + 2), w2w = rlf(w4.w, jj + 2);
            float w3x = rlf(w4.x, jj + 3), w3y = rlf(w4.y, jj + 3), w3z = rlf(w4.z, jj + 3), w3w = rlf(w4.w, jj + 3);
            float w0 = (head & 2) ? ((head & 1) ? w0w : w0z) : ((head & 1) ? w0y : w0x);
            float w1 = (head & 2) ? ((head & 1) ? w1w : w1z) : ((head & 1) ? w1y : w1x);
            float w2 = (head & 2) ? ((head & 1) ? w2w : w2z) : ((head & 1) ? w2y : w2x);
            float w3 = (head & 2) ? ((head & 1) ? w3w : w3z) : ((head & 1) ? w3y : w3x);
            acc.x = fmaf(w0, h0.x, acc.x); acc.y = fmaf(w0, h0.y, acc.y);
            acc.z = fmaf(w0, h0.z, acc.z); acc.w = fmaf(w0, h0.w, acc.w);
            acc.x = fmaf(w1, h1.x, acc.x); acc.y = fmaf(w1, h1.y, acc.y);
            acc.z = fmaf(w1, h1.z, acc.z); acc.w = fmaf(w1, h1.w, acc.w);
            acc.x = fmaf(w2, h2.x, acc.x); acc.y = fmaf(w2, h2.y, acc.y);
            acc.z = fmaf(w2, h2.z, acc.z); acc.w = fmaf(w2, h2.w, acc.w);
            acc.x = fmaf(w3, h3.x, acc.x); acc.y = fmaf(w3, h3.y, acc.y);
            acc.z = fmaf(w3, h3.z, acc.z); acc.w = fmaf(w3, h3.w, acc.w);
        }
    }
    #pragma unroll
    for (int off = 32; off; off >>= 1) {
        Dv.x += __shfl_xor(Dv.x, off);
        Dv.y += __shfl_xor(Dv.y, off);
        Dv.z += __shfl_xor(Dv.z, off);
        Dv.w += __shfl_xor(Dv.w, off);
    }
    float D = (head & 2) ? ((head & 1) ? Dv.w : Dv.z) : ((head & 1) ? Dv.y : Dv.x);
    float inv = 1.0f / (D + 1e-16f);
    float4 o = make_float4(acc.x * inv, acc.y * inv, acc.z * inv, acc.w * inv);
    *(float4*)(outA + (size_t)n * HCC + lane * 4) = o;
}

// ---------------- BN stats ----------------
__global__ void stats_kernel(const float* __restrict__ agg, float* __restrict__ sum,
                             float* __restrict__ ssq) {
    int ch = threadIdx.x;
    float s = 0.f, s2 = 0.f;
    for (int r = blockIdx.x; r < NN; r += gridDim.x) {
        float v = agg[(size_t)r * HCC + ch];
        s += v;
        s2 = fmaf(v, v, s2);
    }
    atomicAdd(&sum[ch], s);
    atomicAdd(&ssq[ch], s2);
}

// bias cancels under batch-stat BN: normalized = (agg - mean_raw)*k + beta
__global__ void bnfin_kernel(const float* __restrict__ sum, const float* __restrict__ ssq,
                             const float* __restrict__ gamma, const float* __restrict__ beta,
                             float* __restrict__ kv, float* __restrict__ cv) {
    int ch = threadIdx.x;
    const float invN = 1.0f / (float)NN;
    float mr = sum[ch] * invN;
    float var = ssq[ch] * invN - mr * mr;
    float k = gamma[ch] * rsqrtf(var + 1e-5f);
    kv[ch] = k;
    cv[ch] = beta[ch] - mr * k;
}

__global__ void norm_kernel(const float* __restrict__ agg, const float* __restrict__ kv,
                            const float* __restrict__ cv, float* __restrict__ xo) {
    size_t idx = (size_t)blockIdx.x * 256 + threadIdx.x;
    size_t i = idx * 4;
    if (i >= NHC) return;
    int ch = (int)(i & 255);
    float4 v = *(const float4*)(agg + i);
    float4 k4 = *(const float4*)(kv + ch);
    float4 c4 = *(const float4*)(cv + ch);
    v.x = fmaxf(fmaf(v.x, k4.x, c4.x), 0.f);
    v.y = fmaxf(fmaf(v.y, k4.y, c4.y), 0.f);
    v.z = fmaxf(fmaf(v.z, k4.z, c4.z), 0.f);
    v.w = fmaxf(fmaf(v.w, k4.w, c4.w), 0.f);
    *(float4*)(xo + i) = v;
}

// ---------------- pooling (batch is sorted: run-length local accumulation) ----
__global__ void pool_kernel(const float* __restrict__ xf, const int* __restrict__ batch,
                            float* __restrict__ pool, int* __restrict__ cnt) {
    int ch = threadIdx.x;
    int nbase = blockIdx.x * 64;
    float acc = 0.f;
    int mc = 0;
    int curg = batch[nbase];
    for (int r = 0; r < 64; ++r) {
        int n = nbase + r;
        if (n >= NN) break;
        int g = batch[n];
        if (g != curg) {
            atomicAdd(&pool[(size_t)curg * HCC + ch], acc);
            if (ch == 0) atomicAdd(&cnt[curg], mc);
            acc = 0.f; mc = 0; curg = g;
        }
        acc += xf[(size_t)n * HCC + ch];
        mc++;
    }
    atomicAdd(&pool[(size_t)curg * HCC + ch], acc);
    if (ch == 0) atomicAdd(&cnt[curg], mc);
}

__global__ void final_kernel(const float* __restrict__ pool, const int* __restrict__ cnt,
                             float* __restrict__ out) {
    int idx = blockIdx.x * 256 + threadIdx.x;
    int g = idx >> 8;
    float c = fmaxf((float)cnt[g], 1.0f);
    out[idx] = pool[idx] / c;
}

// ---------------- launch ----------------
extern "C" void kernel_launch(void* const* d_in, const int* in_sizes, int n_in,
                              void* d_out, int out_size, void* d_ws, size_t ws_size,
                              hipStream_t stream) {
    const float* x = (const float*)d_in[0];
    const int* edge_index = (const int*)d_in[1];
    const int* srcA = edge_index;
    const int* dstA = edge_index + NE;
    const float* edge_attr = (const float*)d_in[2];
    const int* batch = (const int*)d_in[3];
    const float* W[3]   = {(const float*)d_in[4],  (const float*)d_in[10], (const float*)d_in[16]};
    const float* asc[3] = {(const float*)d_in[5],  (const float*)d_in[11], (const float*)d_in[17]};
    const float* adc[3] = {(const float*)d_in[6],  (const float*)d_in[12], (const float*)d_in[18]};
    const float* gam[3] = {(const float*)d_in[8],  (const float*)d_in[14], (const float*)d_in[20]};
    const float* bet[3] = {(const float*)d_in[9],  (const float*)d_in[15], (const float*)d_in[21]};
    const float* We0 = (const float*)d_in[22];
    const float* att_e0 = (const float*)d_in[23];

    float* wsf = (float*)d_ws;
    float* hbuf  = wsf + O_H;
    float* aggb  = wsf + O_AGG;
    float* xcur  = wsf + O_XC;
    float* aE    = wsf + O_AE;
    int*   eid   = (int*)(wsf + O_EID);
    int*   srcP  = (int*)(wsf + O_SRCP);
    int*   dstP  = (int*)(wsf + O_DSTP);
    float* alphaP= wsf + O_ALP;
    int*   startA= (int*)(wsf + O_START);
    int*   cur   = (int*)(wsf + O_CUR);
    float* asA   = wsf + O_AS;
    float* adA   = wsf + O_AD;
    float* Mb    = wsf + O_M;
    float* kv    = wsf + O_KV;
    float* cv    = wsf + O_CV;
    int*   deg   = (int*)(wsf + O_DEG);
    int*   cnt   = (int*)(wsf + O_CNT);
    int*   ctr   = (int*)(wsf + O_CTR);
    float* meanacc = wsf + O_MEAN;
    float* sums  = wsf + O_SUM;
    float* ssqs  = wsf + O_SSQ;
    float* pool  = wsf + O_POOL;

    hipMemsetAsync((void*)(wsf + O_ZERO), 0, (O_END - O_ZERO) * sizeof(float), stream);

    // CSR over dst (shared by all layers)
    deg_kernel<<<(ET + 255) / 256, 256, 0, stream>>>(dstA, deg);
    start_kernel<<<(NN + 255) / 256, 256, 0, stream>>>(deg, startA, cur, ctr);
    scatter_kernel<<<(ET + 255) / 256, 256, 0, stream>>>(srcA, dstA, cur, eid, srcP, dstP);

    // edge attention logits (layer 0 only)
    m_kernel<<<1, 64, 0, stream>>>(We0, att_e0, Mb);
    mean_kernel<<<256, 256, 0, stream>>>(edge_attr, meanacc);
    alphae_kernel<<<(ET + 255) / 256, 256, 0, stream>>>(edge_attr, Mb, meanacc, aE);

    const float* xin = x;
    for (int L = 0; L < 3; ++L) {
        if (L == 0)
            gemm_kernel<128><<<dim3(782, 4), 256, 0, stream>>>(xin, W[L], hbuf, NN);
        else
            gemm_kernel<256><<<dim3(782, 4), 256, 0, stream>>>(xin, W[L], hbuf, NN);
        asad_kernel<<<12500, 256, 0, stream>>>(hbuf, asc[L], adc[L], asA, adA);
        if (L == 0)
            alphap_kernel<true><<<(ET + 255) / 256, 256, 0, stream>>>(srcP, dstP, eid, asA, adA, aE, alphaP);
        else
            alphap_kernel<false><<<(ET + 255) / 256, 256, 0, stream>>>(srcP, dstP, eid, asA, adA, aE, alphaP);
        agg_kernel<<<12500, 256, 0, stream>>>(hbuf, alphaP, srcP, startA, deg, aggb);
        stats_kernel<<<256, 256, 0, stream>>>(aggb, sums + L * 256, ssqs + L * 256);
        bnfin_kernel<<<1, 256, 0, stream>>>(sums + L * 256, ssqs + L * 256, gam[L], bet[L], kv, cv);
        norm_kernel<<<12500, 256, 0, stream>>>(aggb, kv, cv, xcur);
        xin = xcur;
    }

    pool_kernel<<<782, 256, 0, stream>>>(xcur, batch, pool, cnt);
    final_kernel<<<256, 256, 0, stream>>>(pool, cnt, (float*)d_out);
}

// Round 3
// 1085.140 us; speedup vs baseline: 1.2451x; 1.1349x over previous
//
#include <hip/hip_runtime.h>
#include <math.h>

#define NN 50000
#define NE 800000
#define ET 850000   // NE + NN self loops
#define HCC 256     // H*C
#define GG 256

// ---------------- workspace layout (float-element offsets) ----------------
constexpr size_t NHC    = (size_t)NN * HCC;          // 12,800,000
constexpr size_t O_H    = 0;                         // bf16 h [NN,256] (uses half the slot)
constexpr size_t O_AGG  = O_H + NHC;
constexpr size_t O_XC   = O_AGG + NHC;
constexpr size_t O_AE   = O_XC + NHC;                // alphaE [ET,4] (edge-indexed)
constexpr size_t O_EID  = O_AE + (size_t)ET * 4;     // int [ET] CSR pos -> edge id
constexpr size_t O_SRCP = O_EID + ET;                // int [ET] CSR pos -> src node
constexpr size_t O_DSTP = O_SRCP + ET;               // int [ET] CSR pos -> dst node
constexpr size_t O_ALP  = O_DSTP + ET;               // [ET,4] leaky logits, CSR order
constexpr size_t O_START= O_ALP + (size_t)ET * 4;    // int [NN]
constexpr size_t O_CUR  = O_START + NN;              // int [NN]
constexpr size_t O_AS   = O_CUR + NN;                // [NN,4]
constexpr size_t O_AD   = O_AS + (size_t)NN * 4;     // [NN,4]
constexpr size_t O_M    = O_AD + (size_t)NN * 4;     // [16,4]
constexpr size_t O_KV   = O_M + 64;                  // 256
constexpr size_t O_CV   = O_KV + 256;                // 256
// ---- zero zone (single memset) ----
constexpr size_t O_ZERO = O_CV + 256;
constexpr size_t O_DEG  = O_ZERO;                    // int [NN]
constexpr size_t O_CNT  = O_DEG + NN;                // int [GG]
constexpr size_t O_CTR  = O_CNT + GG;                // int [1] (+3 pad)
constexpr size_t O_MEAN = O_CTR + 4;                 // [16]
constexpr size_t O_SUM  = O_MEAN + 16;               // [3*256]
constexpr size_t O_SSQ  = O_SUM + 768;               // [3*256]
constexpr size_t O_POOL = O_SSQ + 768;               // [GG*HCC]
constexpr size_t O_END  = O_POOL + (size_t)GG * HCC;

__device__ inline float rlf(float v, int l) {
    return __int_as_float(__builtin_amdgcn_readlane(__float_as_int(v), l));
}
__device__ inline unsigned short f2bf(float f) {   // RNE
    unsigned int u = __float_as_uint(f);
    unsigned int r = (u + 0x7fffu + ((u >> 16) & 1u)) >> 16;
    return (unsigned short)r;
}
__device__ inline float b2f(unsigned short u) {
    return __uint_as_float(((unsigned int)u) << 16);
}

// ---------------- CSR build ----------------
__global__ void deg_kernel(const int* __restrict__ dstA, int* __restrict__ deg) {
    int e = blockIdx.x * 256 + threadIdx.x;
    if (e >= ET) return;
    int d = (e < NE) ? dstA[e] : (e - NE);
    atomicAdd(&deg[d], 1);
}

__global__ void start_kernel(const int* __restrict__ deg, int* __restrict__ startA,
                             int* __restrict__ cur, int* __restrict__ ctr) {
    int n = blockIdx.x * 256 + threadIdx.x;
    if (n >= NN) return;
    int v = deg[n];
    int s = atomicAdd(ctr, v);
    startA[n] = s;
    cur[n] = s;
}

__global__ void scatter_kernel(const int* __restrict__ srcA, const int* __restrict__ dstA,
                               int* __restrict__ cur, int* __restrict__ eid,
                               int* __restrict__ srcP, int* __restrict__ dstP) {
    int e = blockIdx.x * 256 + threadIdx.x;
    if (e >= ET) return;
    int d = (e < NE) ? dstA[e] : (e - NE);
    int s = (e < NE) ? srcA[e] : (e - NE);
    int p = atomicAdd(&cur[d], 1);
    eid[p] = e;
    srcP[p] = s;
    dstP[p] = d;
}

// ---------------- edge-attention precompute ----------------
__global__ void m_kernel(const float* __restrict__ We0, const float* __restrict__ att_e0,
                         float* __restrict__ M) {
    int t = threadIdx.x;           // 64 threads
    int k = t >> 2, hh = t & 3;
    float s = 0.f;
    for (int c = 0; c < 64; ++c)
        s += We0[k * 256 + hh * 64 + c] * att_e0[hh * 64 + c];
    M[k * 4 + hh] = s;
}

__global__ void mean_kernel(const float* __restrict__ ea, float* __restrict__ meanacc) {
    __shared__ float part[256];
    int col = threadIdx.x & 15, rl = threadIdx.x >> 4;
    float s = 0.f;
    for (size_t r = (size_t)blockIdx.x * 16 + rl; r < NE; r += (size_t)gridDim.x * 16)
        s += ea[r * 16 + col];
    part[threadIdx.x] = s;
    __syncthreads();
    if (threadIdx.x < 16) {
        float t = 0.f;
        for (int j = 0; j < 16; ++j) t += part[threadIdx.x + j * 16];
        atomicAdd(&meanacc[threadIdx.x], t);
    }
}

__global__ void alphae_kernel(const float* __restrict__ ea, const float* __restrict__ M,
                              const float* __restrict__ meanacc, float* __restrict__ aE) {
    size_t e = (size_t)blockIdx.x * 256 + threadIdx.x;
    if (e >= ET) return;
    float v[16];
    if (e < NE) {
        const float4* p = (const float4*)(ea + e * 16);
        float4 a = p[0], b = p[1], c = p[2], d = p[3];
        v[0]=a.x; v[1]=a.y; v[2]=a.z; v[3]=a.w;
        v[4]=b.x; v[5]=b.y; v[6]=b.z; v[7]=b.w;
        v[8]=c.x; v[9]=c.y; v[10]=c.z; v[11]=c.w;
        v[12]=d.x; v[13]=d.y; v[14]=d.z; v[15]=d.w;
    } else {
        const float inv = 1.0f / (float)NE;
        #pragma unroll
        for (int k = 0; k < 16; ++k) v[k] = meanacc[k] * inv;
    }
    float o[4] = {0.f, 0.f, 0.f, 0.f};
    #pragma unroll
    for (int k = 0; k < 16; ++k) {
        float4 m4 = *(const float4*)(M + k * 4);
        o[0] = fmaf(v[k], m4.x, o[0]);
        o[1] = fmaf(v[k], m4.y, o[1]);
        o[2] = fmaf(v[k], m4.z, o[2]);
        o[3] = fmaf(v[k], m4.w, o[3]);
    }
    *(float4*)(aE + e * 4) = make_float4(o[0], o[1], o[2], o[3]);
}

// ---------------- per-edge leaky logits in CSR order ----------------
template <bool HAS_AE>
__global__ void alphap_kernel(const int* __restrict__ srcP, const int* __restrict__ dstP,
                              const int* __restrict__ eid, const float* __restrict__ asA,
                              const float* __restrict__ adA, const float* __restrict__ aE,
                              float* __restrict__ alphaP) {
    size_t p = (size_t)blockIdx.x * 256 + threadIdx.x;
    if (p >= ET) return;
    int s = srcP[p], d = dstP[p];
    float4 av = *(const float4*)(asA + (size_t)s * 4);
    float4 dv = *(const float4*)(adA + (size_t)d * 4);
    float4 t = make_float4(av.x + dv.x, av.y + dv.y, av.z + dv.z, av.w + dv.w);
    if (HAS_AE) {
        int e = eid[p];
        float4 e4 = *(const float4*)(aE + (size_t)e * 4);
        t.x += e4.x; t.y += e4.y; t.z += e4.z; t.w += e4.w;
    }
    t.x = (t.x > 0.f) ? t.x : 0.2f * t.x;
    t.y = (t.y > 0.f) ? t.y : 0.2f * t.y;
    t.z = (t.z > 0.f) ? t.z : 0.2f * t.z;
    t.w = (t.w > 0.f) ? t.w : 0.2f * t.w;
    *(float4*)(alphaP + p * 4) = t;
}

// ---------------- GEMM: h = A[M,K] @ B[K,256], bf16 output ----------------
template <int K>
__global__ __launch_bounds__(256) void gemm_kernel(const float* __restrict__ A,
                                                   const float* __restrict__ B,
                                                   unsigned short* __restrict__ Hout, int M) {
    __shared__ float As[16][68];   // [k][row], padded
    __shared__ float Bs[16][64];   // [k][col]
    int tid = threadIdx.x;
    int row0 = blockIdx.x * 64;
    int col0 = blockIdx.y * 64;
    int tx = tid & 15, ty = tid >> 4;
    int arow = tid >> 2, ak = (tid & 3) * 4;
    float acc[4][4] = {};
    for (int kt = 0; kt < K; kt += 16) {
        float4 av = make_float4(0.f, 0.f, 0.f, 0.f);
        if (row0 + arow < M)
            av = *(const float4*)(A + (size_t)(row0 + arow) * K + kt + ak);
        As[ak + 0][arow] = av.x;
        As[ak + 1][arow] = av.y;
        As[ak + 2][arow] = av.z;
        As[ak + 3][arow] = av.w;
        float4 bv = *(const float4*)(B + (size_t)(kt + ty) * HCC + col0 + tx * 4);
        *(float4*)&Bs[ty][tx * 4] = bv;
        __syncthreads();
        #pragma unroll
        for (int kk = 0; kk < 16; ++kk) {
            float4 a = *(const float4*)&As[kk][ty * 4];
            float4 b = *(const float4*)&Bs[kk][tx * 4];
            acc[0][0] = fmaf(a.x, b.x, acc[0][0]);
            acc[0][1] = fmaf(a.x, b.y, acc[0][1]);
            acc[0][2] = fmaf(a.x, b.z, acc[0][2]);
            acc[0][3] = fmaf(a.x, b.w, acc[0][3]);
            acc[1][0] = fmaf(a.y, b.x, acc[1][0]);
            acc[1][1] = fmaf(a.y, b.y, acc[1][1]);
            acc[1][2] = fmaf(a.y, b.z, acc[1][2]);
            acc[1][3] = fmaf(a.y, b.w, acc[1][3]);
            acc[2][0] = fmaf(a.z, b.x, acc[2][0]);
            acc[2][1] = fmaf(a.z, b.y, acc[2][1]);
            acc[2][2] = fmaf(a.z, b.z, acc[2][2]);
            acc[2][3] = fmaf(a.z, b.w, acc[2][3]);
            acc[3][0] = fmaf(a.w, b.x, acc[3][0]);
            acc[3][1] = fmaf(a.w, b.y, acc[3][1]);
            acc[3][2] = fmaf(a.w, b.z, acc[3][2]);
            acc[3][3] = fmaf(a.w, b.w, acc[3][3]);
        }
        __syncthreads();
    }
    #pragma unroll
    for (int i = 0; i < 4; ++i) {
        int r = row0 + ty * 4 + i;
        if (r < M) {
            ushort4 o;
            o.x = f2bf(acc[i][0]); o.y = f2bf(acc[i][1]);
            o.z = f2bf(acc[i][2]); o.w = f2bf(acc[i][3]);
            *(ushort4*)(Hout + (size_t)r * HCC + col0 + tx * 4) = o;
        }
    }
}

// ---------------- per-node attention logits (bf16 h) ----------------
__global__ void asad_kernel(const unsigned short* __restrict__ Hm,
                            const float* __restrict__ att_src,
                            const float* __restrict__ att_dst, float* __restrict__ asA,
                            float* __restrict__ adA) {
    int wave = threadIdx.x >> 6, lane = threadIdx.x & 63;
    int n = blockIdx.x * 4 + wave;
    if (n >= NN) return;
    int head = lane >> 4;
    int ci = (lane & 15) * 4;
    ushort4 hv4 = *(const ushort4*)(Hm + (size_t)n * HCC + lane * 4);
    float hx = b2f(hv4.x), hy = b2f(hv4.y), hz = b2f(hv4.z), hw = b2f(hv4.w);
    float4 s4 = *(const float4*)(att_src + head * 64 + ci);
    float4 d4 = *(const float4*)(att_dst + head * 64 + ci);
    float ps = hx * s4.x + hy * s4.y + hz * s4.z + hw * s4.w;
    float pd = hx * d4.x + hy * d4.y + hz * d4.z + hw * d4.w;
    #pragma unroll
    for (int off = 8; off; off >>= 1) {
        ps += __shfl_xor(ps, off);
        pd += __shfl_xor(pd, off);
    }
    if ((lane & 15) == 0) {
        asA[n * 4 + head] = ps;
        adA[n * 4 + head] = pd;
    }
}

// ---------------- per-node softmax aggregation (wave per node, CSR-ordered) --
__global__ __launch_bounds__(256) void agg_kernel(const unsigned short* __restrict__ Hm,
                                                  const float* __restrict__ alphaP,
                                                  const int* __restrict__ srcP,
                                                  const int* __restrict__ startA,
                                                  const int* __restrict__ degA,
                                                  float* __restrict__ outA) {
    int wave = threadIdx.x >> 6, lane = threadIdx.x & 63;
    int n = blockIdx.x * 4 + wave;
    if (n >= NN) return;
    int head = lane >> 4;
    int st = startA[n];
    int d = degA[n];

    // pass 1: component-wise max over edges (lane j <-> edge j)
    float4 m4 = make_float4(-1e30f, -1e30f, -1e30f, -1e30f);
    for (int j = lane; j < d; j += 64) {
        float4 a = *(const float4*)(alphaP + (size_t)(st + j) * 4);
        m4.x = fmaxf(m4.x, a.x); m4.y = fmaxf(m4.y, a.y);
        m4.z = fmaxf(m4.z, a.z); m4.w = fmaxf(m4.w, a.w);
    }
    #pragma unroll
    for (int off = 32; off; off >>= 1) {
        m4.x = fmaxf(m4.x, __shfl_xor(m4.x, off));
        m4.y = fmaxf(m4.y, __shfl_xor(m4.y, off));
        m4.z = fmaxf(m4.z, __shfl_xor(m4.z, off));
        m4.w = fmaxf(m4.w, __shfl_xor(m4.w, off));
    }

    // pass 2: chunks of 64 edges; w in registers, broadcast via readlane;
    // 8 gather loads in flight per group.
    float4 Dv = make_float4(0.f, 0.f, 0.f, 0.f);
    float4 acc = make_float4(0.f, 0.f, 0.f, 0.f);
    const unsigned short* hb = Hm + lane * 4;
    for (int base = 0; base < d; base += 64) {
        int j = base + lane;
        float4 a4 = make_float4(-1e30f, -1e30f, -1e30f, -1e30f);
        int ms = 0;
        if (j < d) {
            a4 = *(const float4*)(alphaP + (size_t)(st + j) * 4);
            ms = srcP[st + j];
        }
        float4 w4;
        w4.x = __expf(a4.x - m4.x);   // 0 for out-of-range lanes
        w4.y = __expf(a4.y - m4.y);
        w4.z = __expf(a4.z - m4.z);
        w4.w = __expf(a4.w - m4.w);
        Dv.x += w4.x; Dv.y += w4.y; Dv.z += w4.z; Dv.w += w4.w;

        int cnt = d - base; if (cnt > 64) cnt = 64;
        int cnt8 = (cnt + 7) & ~7;    // padded lanes have w=0, safe (ms=0 -> row 0)
        for (int jj = 0; jj < cnt8; jj += 8) {
            int sj[8];
            #pragma unroll
            for (int q = 0; q < 8; ++q)
                sj[q] = __builtin_amdgcn_readlane(ms, jj + q);
            ushort4 hv[8];
            #pragma unroll
            for (int q = 0; q < 8; ++q)
                hv[q] = *(const ushort4*)(hb + (size_t)sj[q] * HCC);
            #pragma unroll
            for (int q = 0; q < 8; ++q) {
                float wx = rlf(w4.x, jj + q), wy = rlf(w4.y, jj + q);
                float wz = rlf(w4.z, jj + q), ww = rlf(w4.w, jj + q);
                float w = (head & 2) ? ((head & 1) ? ww : wz) : ((head & 1) ? wy : wx);
                acc.x = fmaf(w, b2f(hv[q].x), acc.x);
                acc.y = fmaf(w, b2f(hv[q].y), acc.y);
                acc.z = fmaf(w, b2f(hv[q].z), acc.z);
                acc.w = fmaf(w, b2f(hv[q].w), acc.w);
            }
        }
    }
    #pragma unroll
    for (int off = 32; off; off >>= 1) {
        Dv.x += __shfl_xor(Dv.x, off);
        Dv.y += __shfl_xor(Dv.y, off);
        Dv.z += __shfl_xor(Dv.z, off);
        Dv.w += __shfl_xor(Dv.w, off);
    }
    float D = (head & 2) ? ((head & 1) ? Dv.w : Dv.z) : ((head & 1) ? Dv.y : Dv.x);
    float inv = 1.0f / (D + 1e-16f);
    float4 o = make_float4(acc.x * inv, acc.y * inv, acc.z * inv, acc.w * inv);
    *(float4*)(outA + (size_t)n * HCC + lane * 4) = o;
}

// ---------------- BN stats ----------------
__global__ void stats_kernel(const float* __restrict__ agg, float* __restrict__ sum,
                             float* __restrict__ ssq) {
    int ch = threadIdx.x;
    float s = 0.f, s2 = 0.f;
    for (int r = blockIdx.x; r < NN; r += gridDim.x) {
        float v = agg[(size_t)r * HCC + ch];
        s += v;
        s2 = fmaf(v, v, s2);
    }
    atomicAdd(&sum[ch], s);
    atomicAdd(&ssq[ch], s2);
}

// bias cancels under batch-stat BN: normalized = (agg - mean_raw)*k + beta
__global__ void bnfin_kernel(const float* __restrict__ sum, const float* __restrict__ ssq,
                             const float* __restrict__ gamma, const float* __restrict__ beta,
                             float* __restrict__ kv, float* __restrict__ cv) {
    int ch = threadIdx.x;
    const float invN = 1.0f / (float)NN;
    float mr = sum[ch] * invN;
    float var = ssq[ch] * invN - mr * mr;
    float k = gamma[ch] * rsqrtf(var + 1e-5f);
    kv[ch] = k;
    cv[ch] = beta[ch] - mr * k;
}

__global__ void norm_kernel(const float* __restrict__ agg, const float* __restrict__ kv,
                            const float* __restrict__ cv, float* __restrict__ xo) {
    size_t idx = (size_t)blockIdx.x * 256 + threadIdx.x;
    size_t i = idx * 4;
    if (i >= NHC) return;
    int ch = (int)(i & 255);
    float4 v = *(const float4*)(agg + i);
    float4 k4 = *(const float4*)(kv + ch);
    float4 c4 = *(const float4*)(cv + ch);
    v.x = fmaxf(fmaf(v.x, k4.x, c4.x), 0.f);
    v.y = fmaxf(fmaf(v.y, k4.y, c4.y), 0.f);
    v.z = fmaxf(fmaf(v.z, k4.z, c4.z), 0.f);
    v.w = fmaxf(fmaf(v.w, k4.w, c4.w), 0.f);
    *(float4*)(xo + i) = v;
}

// ---------------- pooling (batch is sorted: run-length local accumulation) ----
__global__ void pool_kernel(const float* __restrict__ xf, const int* __restrict__ batch,
                            float* __restrict__ pool, int* __restrict__ cnt) {
    int ch = threadIdx.x;
    int nbase = blockIdx.x * 64;
    float acc = 0.f;
    int mc = 0;
    int curg = batch[nbase];
    for (int r = 0; r < 64; ++r) {
        int n = nbase + r;
        if (n >= NN) break;
        int g = batch[n];
        if (g != curg) {
            atomicAdd(&pool[(size_t)curg * HCC + ch], acc);
            if (ch == 0) atomicAdd(&cnt[curg], mc);
            acc = 0.f; mc = 0; curg = g;
        }
        acc += xf[(size_t)n * HCC + ch];
        mc++;
    }
    atomicAdd(&pool[(size_t)curg * HCC + ch], acc);
    if (ch == 0) atomicAdd(&cnt[curg], mc);
}

__global__ void final_kernel(const float* __restrict__ pool, const int* __restrict__ cnt,
                             float* __restrict__ out) {
    int idx = blockIdx.x * 256 + threadIdx.x;
    int g = idx >> 8;
    float c = fmaxf((float)cnt[g], 1.0f);
    out[idx] = pool[idx] / c;
}

// ---------------- launch ----------------
extern "C" void kernel_launch(void* const* d_in, const int* in_sizes, int n_in,
                              void* d_out, int out_size, void* d_ws, size_t ws_size,
                              hipStream_t stream) {
    const float* x = (const float*)d_in[0];
    const int* edge_index = (const int*)d_in[1];
    const int* srcA = edge_index;
    const int* dstA = edge_index + NE;
    const float* edge_attr = (const float*)d_in[2];
    const int* batch = (const int*)d_in[3];
    const float* W[3]   = {(const float*)d_in[4],  (const float*)d_in[10], (const float*)d_in[16]};
    const float* asc[3] = {(const float*)d_in[5],  (const float*)d_in[11], (const float*)d_in[17]};
    const float* adc[3] = {(const float*)d_in[6],  (const float*)d_in[12], (const float*)d_in[18]};
    const float* gam[3] = {(const float*)d_in[8],  (const float*)d_in[14], (const float*)d_in[20]};
    const float* bet[3] = {(const float*)d_in[9],  (const float*)d_in[15], (const float*)d_in[21]};
    const float* We0 = (const float*)d_in[22];
    const float* att_e0 = (const float*)d_in[23];

    float* wsf = (float*)d_ws;
    unsigned short* hbuf = (unsigned short*)(wsf + O_H);
    float* aggb  = wsf + O_AGG;
    float* xcur  = wsf + O_XC;
    float* aE    = wsf + O_AE;
    int*   eid   = (int*)(wsf + O_EID);
    int*   srcP  = (int*)(wsf + O_SRCP);
    int*   dstP  = (int*)(wsf + O_DSTP);
    float* alphaP= wsf + O_ALP;
    int*   startA= (int*)(wsf + O_START);
    int*   cur   = (int*)(wsf + O_CUR);
    float* asA   = wsf + O_AS;
    float* adA   = wsf + O_AD;
    float* Mb    = wsf + O_M;
    float* kv    = wsf + O_KV;
    float* cv    = wsf + O_CV;
    int*   deg   = (int*)(wsf + O_DEG);
    int*   cnt   = (int*)(wsf + O_CNT);
    int*   ctr   = (int*)(wsf + O_CTR);
    float* meanacc = wsf + O_MEAN;
    float* sums  = wsf + O_SUM;
    float* ssqs  = wsf + O_SSQ;
    float* pool  = wsf + O_POOL;

    hipMemsetAsync((void*)(wsf + O_ZERO), 0, (O_END - O_ZERO) * sizeof(float), stream);

    // CSR over dst (shared by all layers)
    deg_kernel<<<(ET + 255) / 256, 256, 0, stream>>>(dstA, deg);
    start_kernel<<<(NN + 255) / 256, 256, 0, stream>>>(deg, startA, cur, ctr);
    scatter_kernel<<<(ET + 255) / 256, 256, 0, stream>>>(srcA, dstA, cur, eid, srcP, dstP);

    // edge attention logits (layer 0 only)
    m_kernel<<<1, 64, 0, stream>>>(We0, att_e0, Mb);
    mean_kernel<<<256, 256, 0, stream>>>(edge_attr, meanacc);
    alphae_kernel<<<(ET + 255) / 256, 256, 0, stream>>>(edge_attr, Mb, meanacc, aE);

    const float* xin = x;
    for (int L = 0; L < 3; ++L) {
        if (L == 0)
            gemm_kernel<128><<<dim3(782, 4), 256, 0, stream>>>(xin, W[L], hbuf, NN);
        else
            gemm_kernel<256><<<dim3(782, 4), 256, 0, stream>>>(xin, W[L], hbuf, NN);
        asad_kernel<<<12500, 256, 0, stream>>>(hbuf, asc[L], adc[L], asA, adA);
        if (L == 0)
            alphap_kernel<true><<<(ET + 255) / 256, 256, 0, stream>>>(srcP, dstP, eid, asA, adA, aE, alphaP);
        else
            alphap_kernel<false><<<(ET + 255) / 256, 256, 0, stream>>>(srcP, dstP, eid, asA, adA, aE, alphaP);
        agg_kernel<<<12500, 256, 0, stream>>>(hbuf, alphaP, srcP, startA, deg, aggb);
        stats_kernel<<<256, 256, 0, stream>>>(aggb, sums + L * 256, ssqs + L * 256);
        bnfin_kernel<<<1, 256, 0, stream>>>(sums + L * 256, ssqs + L * 256, gam[L], bet[L], kv, cv);
        norm_kernel<<<12500, 256, 0, stream>>>(aggb, kv, cv, xcur);
        xin = xcur;
    }

    pool_kernel<<<782, 256, 0, stream>>>(xcur, batch, pool, cnt);
    final_kernel<<<256, 256, 0, stream>>>(pool, cnt, (float*)d_out);
}

// Round 4
// 905.204 us; speedup vs baseline: 1.4926x; 1.1988x over previous
//
#include <hip/hip_runtime.h>
#include <math.h>

#define NN 50000
#define NE 800000
#define ET 850000   // NE + NN self loops
#define HCC 256     // H*C
#define GG 256

// ---------------- workspace layout (float-element offsets) ----------------
constexpr size_t NHC    = (size_t)NN * HCC;          // 12,800,000
constexpr size_t O_H    = 0;                         // bf16 h [NN,256] (half the slot)
constexpr size_t O_XB   = O_H + NHC / 2;             // bf16 x [NN,128] (upper half of h slot)
constexpr size_t O_AGG  = O_H + NHC;
constexpr size_t O_XC   = O_AGG + NHC;               // bf16 xcur [NN,256] (half the slot)
constexpr size_t O_BT   = O_XC + NHC / 2;            // bf16 Bt [256,256] (upper half)
constexpr size_t O_AE   = O_XC + NHC;                // alphaE [ET,4] (edge-indexed)
constexpr size_t O_EID  = O_AE + (size_t)ET * 4;     // int [ET] CSR pos -> edge id
constexpr size_t O_SRCP = O_EID + ET;                // int [ET] CSR pos -> src node
constexpr size_t O_DSTP = O_SRCP + ET;               // int [ET] CSR pos -> dst node
constexpr size_t O_ALP  = O_DSTP + ET;               // [ET,4] leaky logits, CSR order
constexpr size_t O_START= O_ALP + (size_t)ET * 4;    // int [NN]
constexpr size_t O_CUR  = O_START + NN;              // int [NN]
constexpr size_t O_AS   = O_CUR + NN;                // [NN,4]
constexpr size_t O_AD   = O_AS + (size_t)NN * 4;     // [NN,4]
constexpr size_t O_M    = O_AD + (size_t)NN * 4;     // [16,4]
constexpr size_t O_KV   = O_M + 64;                  // 256
constexpr size_t O_CV   = O_KV + 256;                // 256
// ---- zero zone (single memset) ----
constexpr size_t O_ZERO = O_CV + 256;
constexpr size_t O_DEG  = O_ZERO;                    // int [NN]
constexpr size_t O_CNT  = O_DEG + NN;                // int [GG]
constexpr size_t O_CTR  = O_CNT + GG;                // int [1] (+3 pad)
constexpr size_t O_MEAN = O_CTR + 4;                 // [16]
constexpr size_t O_SUM  = O_MEAN + 16;               // [3*256]
constexpr size_t O_SSQ  = O_SUM + 768;               // [3*256]
constexpr size_t O_POOL = O_SSQ + 768;               // [GG*HCC]
constexpr size_t O_END  = O_POOL + (size_t)GG * HCC;

typedef __attribute__((ext_vector_type(8))) short bf16x8;
typedef __attribute__((ext_vector_type(4))) float f32x4;

__device__ inline float rlf(float v, int l) {
    return __int_as_float(__builtin_amdgcn_readlane(__float_as_int(v), l));
}
__device__ inline unsigned short f2bf(float f) {   // RNE
    unsigned int u = __float_as_uint(f);
    unsigned int r = (u + 0x7fffu + ((u >> 16) & 1u)) >> 16;
    return (unsigned short)r;
}
__device__ inline float b2f(unsigned short u) {
    return __uint_as_float(((unsigned int)u) << 16);
}

// ---------------- CSR build ----------------
__global__ void deg_kernel(const int* __restrict__ dstA, int* __restrict__ deg) {
    int e = blockIdx.x * 256 + threadIdx.x;
    if (e >= ET) return;
    int d = (e < NE) ? dstA[e] : (e - NE);
    atomicAdd(&deg[d], 1);
}

__global__ void start_kernel(const int* __restrict__ deg, int* __restrict__ startA,
                             int* __restrict__ cur, int* __restrict__ ctr) {
    int n = blockIdx.x * 256 + threadIdx.x;
    if (n >= NN) return;
    int v = deg[n];
    int s = atomicAdd(ctr, v);
    startA[n] = s;
    cur[n] = s;
}

__global__ void scatter_kernel(const int* __restrict__ srcA, const int* __restrict__ dstA,
                               int* __restrict__ cur, int* __restrict__ eid,
                               int* __restrict__ srcP, int* __restrict__ dstP) {
    int e = blockIdx.x * 256 + threadIdx.x;
    if (e >= ET) return;
    int d = (e < NE) ? dstA[e] : (e - NE);
    int s = (e < NE) ? srcA[e] : (e - NE);
    int p = atomicAdd(&cur[d], 1);
    eid[p] = e;
    srcP[p] = s;
    dstP[p] = d;
}

// ---------------- dtype conversion ----------------
__global__ void cvt_x_kernel(const float* __restrict__ x, unsigned short* __restrict__ xb) {
    size_t i = ((size_t)blockIdx.x * 256 + threadIdx.x) * 4;   // 6,400,000 total
    float4 v = *(const float4*)(x + i);
    ushort4 o;
    o.x = f2bf(v.x); o.y = f2bf(v.y); o.z = f2bf(v.z); o.w = f2bf(v.w);
    *(ushort4*)(xb + i) = o;
}

// W [K,256] fp32 -> Bt [256,K] bf16 (transposed)
__global__ void cvt_w_kernel(const float* __restrict__ W, unsigned short* __restrict__ Bt, int K) {
    int idx = blockIdx.x * 256 + threadIdx.x;   // K*256 threads
    int n = idx & 255, k = idx >> 8;
    Bt[(size_t)n * K + k] = f2bf(W[(size_t)k * 256 + n]);
}

// ---------------- edge-attention precompute ----------------
__global__ void m_kernel(const float* __restrict__ We0, const float* __restrict__ att_e0,
                         float* __restrict__ M) {
    int t = threadIdx.x;           // 64 threads
    int k = t >> 2, hh = t & 3;
    float s = 0.f;
    for (int c = 0; c < 64; ++c)
        s += We0[k * 256 + hh * 64 + c] * att_e0[hh * 64 + c];
    M[k * 4 + hh] = s;
}

__global__ void mean_kernel(const float* __restrict__ ea, float* __restrict__ meanacc) {
    __shared__ float part[256];
    int col = threadIdx.x & 15, rl = threadIdx.x >> 4;
    float s = 0.f;
    for (size_t r = (size_t)blockIdx.x * 16 + rl; r < NE; r += (size_t)gridDim.x * 16)
        s += ea[r * 16 + col];
    part[threadIdx.x] = s;
    __syncthreads();
    if (threadIdx.x < 16) {
        float t = 0.f;
        for (int j = 0; j < 16; ++j) t += part[threadIdx.x + j * 16];
        atomicAdd(&meanacc[threadIdx.x], t);
    }
}

__global__ void alphae_kernel(const float* __restrict__ ea, const float* __restrict__ M,
                              const float* __restrict__ meanacc, float* __restrict__ aE) {
    size_t e = (size_t)blockIdx.x * 256 + threadIdx.x;
    if (e >= ET) return;
    float v[16];
    if (e < NE) {
        const float4* p = (const float4*)(ea + e * 16);
        float4 a = p[0], b = p[1], c = p[2], d = p[3];
        v[0]=a.x; v[1]=a.y; v[2]=a.z; v[3]=a.w;
        v[4]=b.x; v[5]=b.y; v[6]=b.z; v[7]=b.w;
        v[8]=c.x; v[9]=c.y; v[10]=c.z; v[11]=c.w;
        v[12]=d.x; v[13]=d.y; v[14]=d.z; v[15]=d.w;
    } else {
        const float inv = 1.0f / (float)NE;
        #pragma unroll
        for (int k = 0; k < 16; ++k) v[k] = meanacc[k] * inv;
    }
    float o[4] = {0.f, 0.f, 0.f, 0.f};
    #pragma unroll
    for (int k = 0; k < 16; ++k) {
        float4 m4 = *(const float4*)(M + k * 4);
        o[0] = fmaf(v[k], m4.x, o[0]);
        o[1] = fmaf(v[k], m4.y, o[1]);
        o[2] = fmaf(v[k], m4.z, o[2]);
        o[3] = fmaf(v[k], m4.w, o[3]);
    }
    *(float4*)(aE + e * 4) = make_float4(o[0], o[1], o[2], o[3]);
}

// ---------------- per-edge leaky logits in CSR order ----------------
template <bool HAS_AE>
__global__ void alphap_kernel(const int* __restrict__ srcP, const int* __restrict__ dstP,
                              const int* __restrict__ eid, const float* __restrict__ asA,
                              const float* __restrict__ adA, const float* __restrict__ aE,
                              float* __restrict__ alphaP) {
    size_t p = (size_t)blockIdx.x * 256 + threadIdx.x;
    if (p >= ET) return;
    int s = srcP[p], d = dstP[p];
    float4 av = *(const float4*)(asA + (size_t)s * 4);
    float4 dv = *(const float4*)(adA + (size_t)d * 4);
    float4 t = make_float4(av.x + dv.x, av.y + dv.y, av.z + dv.z, av.w + dv.w);
    if (HAS_AE) {
        int e = eid[p];
        float4 e4 = *(const float4*)(aE + (size_t)e * 4);
        t.x += e4.x; t.y += e4.y; t.z += e4.z; t.w += e4.w;
    }
    t.x = (t.x > 0.f) ? t.x : 0.2f * t.x;
    t.y = (t.y > 0.f) ? t.y : 0.2f * t.y;
    t.z = (t.z > 0.f) ? t.z : 0.2f * t.z;
    t.w = (t.w > 0.f) ? t.w : 0.2f * t.w;
    *(float4*)(alphaP + p * 4) = t;
}

// ---------------- MFMA GEMM: H[M,256] = A[M,K](bf16) @ Bt[256,K](bf16)^T ----
// Block: 256 thr = 4 waves. Tile: 64 rows x 256 cols; wave w owns cols [64w,64w+64)
// as 4x4 grid of 16x16x32 bf16 MFMA fragments.
template <int K>
__global__ __launch_bounds__(256) void gemm_mfma(const unsigned short* __restrict__ A,
                                                 const unsigned short* __restrict__ Bt,
                                                 unsigned short* __restrict__ Hout, int M) {
    __shared__ unsigned short As[64][40];    // pad 40 -> 80B row stride (16B aligned, 2-way banks)
    __shared__ unsigned short Bs[256][40];   // Bs[n][k] = B^T
    int tid = threadIdx.x;
    int wave = tid >> 6, lane = tid & 63;
    int quad = lane >> 4, l16 = lane & 15;
    int row0 = blockIdx.x * 64;
    f32x4 acc[4][4] = {};                    // [mi][ni]

    for (int k0 = 0; k0 < K; k0 += 32) {
        // stage A: 64 rows x 32 k; thread t -> row t>>2, 16B segment t&3
        {
            int row = tid >> 2, seg = tid & 3;
            uint4 v = make_uint4(0u, 0u, 0u, 0u);
            if (row0 + row < M)
                v = *(const uint4*)(A + (size_t)(row0 + row) * K + k0 + seg * 8);
            *(uint4*)&As[row][seg * 8] = v;
        }
        // stage B^T: 256 cols x 32 k; thread t -> col t (64B)
        {
            const uint4* src = (const uint4*)(Bt + (size_t)tid * K + k0);
            uint4 b0 = src[0], b1 = src[1], b2 = src[2], b3 = src[3];
            uint4* dst = (uint4*)&Bs[tid][0];
            dst[0] = b0; dst[1] = b1; dst[2] = b2; dst[3] = b3;
        }
        __syncthreads();
        bf16x8 a_frag[4], b_frag[4];
        #pragma unroll
        for (int mi = 0; mi < 4; ++mi)
            a_frag[mi] = *(const bf16x8*)&As[mi * 16 + l16][quad * 8];
        #pragma unroll
        for (int ni = 0; ni < 4; ++ni)
            b_frag[ni] = *(const bf16x8*)&Bs[wave * 64 + ni * 16 + l16][quad * 8];
        #pragma unroll
        for (int mi = 0; mi < 4; ++mi)
            #pragma unroll
            for (int ni = 0; ni < 4; ++ni)
                acc[mi][ni] = __builtin_amdgcn_mfma_f32_16x16x32_bf16(
                    a_frag[mi], b_frag[ni], acc[mi][ni], 0, 0, 0);
        __syncthreads();
    }

    // epilogue: C/D layout col=lane&15, row=quad*4+reg
    #pragma unroll
    for (int mi = 0; mi < 4; ++mi) {
        #pragma unroll
        for (int reg = 0; reg < 4; ++reg) {
            int r = row0 + mi * 16 + quad * 4 + reg;
            if (r < M) {
                #pragma unroll
                for (int ni = 0; ni < 4; ++ni) {
                    int c = wave * 64 + ni * 16 + l16;
                    Hout[(size_t)r * HCC + c] = f2bf(acc[mi][ni][reg]);
                }
            }
        }
    }
}

// ---------------- per-node attention logits (bf16 h) ----------------
__global__ void asad_kernel(const unsigned short* __restrict__ Hm,
                            const float* __restrict__ att_src,
                            const float* __restrict__ att_dst, float* __restrict__ asA,
                            float* __restrict__ adA) {
    int wave = threadIdx.x >> 6, lane = threadIdx.x & 63;
    int n = blockIdx.x * 4 + wave;
    if (n >= NN) return;
    int head = lane >> 4;
    int ci = (lane & 15) * 4;
    ushort4 hv4 = *(const ushort4*)(Hm + (size_t)n * HCC + lane * 4);
    float hx = b2f(hv4.x), hy = b2f(hv4.y), hz = b2f(hv4.z), hw = b2f(hv4.w);
    float4 s4 = *(const float4*)(att_src + head * 64 + ci);
    float4 d4 = *(const float4*)(att_dst + head * 64 + ci);
    float ps = hx * s4.x + hy * s4.y + hz * s4.z + hw * s4.w;
    float pd = hx * d4.x + hy * d4.y + hz * d4.z + hw * d4.w;
    #pragma unroll
    for (int off = 8; off; off >>= 1) {
        ps += __shfl_xor(ps, off);
        pd += __shfl_xor(pd, off);
    }
    if ((lane & 15) == 0) {
        asA[n * 4 + head] = ps;
        adA[n * 4 + head] = pd;
    }
}

// ---------------- per-node softmax aggregation (wave per node, CSR-ordered) --
__global__ __launch_bounds__(256) void agg_kernel(const unsigned short* __restrict__ Hm,
                                                  const float* __restrict__ alphaP,
                                                  const int* __restrict__ srcP,
                                                  const int* __restrict__ startA,
                                                  const int* __restrict__ degA,
                                                  float* __restrict__ outA) {
    int wave = threadIdx.x >> 6, lane = threadIdx.x & 63;
    int n = blockIdx.x * 4 + wave;
    if (n >= NN) return;
    int head = lane >> 4;
    int st = startA[n];
    int d = degA[n];

    float4 m4 = make_float4(-1e30f, -1e30f, -1e30f, -1e30f);
    for (int j = lane; j < d; j += 64) {
        float4 a = *(const float4*)(alphaP + (size_t)(st + j) * 4);
        m4.x = fmaxf(m4.x, a.x); m4.y = fmaxf(m4.y, a.y);
        m4.z = fmaxf(m4.z, a.z); m4.w = fmaxf(m4.w, a.w);
    }
    #pragma unroll
    for (int off = 32; off; off >>= 1) {
        m4.x = fmaxf(m4.x, __shfl_xor(m4.x, off));
        m4.y = fmaxf(m4.y, __shfl_xor(m4.y, off));
        m4.z = fmaxf(m4.z, __shfl_xor(m4.z, off));
        m4.w = fmaxf(m4.w, __shfl_xor(m4.w, off));
    }

    float4 Dv = make_float4(0.f, 0.f, 0.f, 0.f);
    float4 acc = make_float4(0.f, 0.f, 0.f, 0.f);
    const unsigned short* hb = Hm + lane * 4;
    for (int base = 0; base < d; base += 64) {
        int j = base + lane;
        float4 a4 = make_float4(-1e30f, -1e30f, -1e30f, -1e30f);
        int ms = 0;
        if (j < d) {
            a4 = *(const float4*)(alphaP + (size_t)(st + j) * 4);
            ms = srcP[st + j];
        }
        float4 w4;
        w4.x = __expf(a4.x - m4.x);
        w4.y = __expf(a4.y - m4.y);
        w4.z = __expf(a4.z - m4.z);
        w4.w = __expf(a4.w - m4.w);
        Dv.x += w4.x; Dv.y += w4.y; Dv.z += w4.z; Dv.w += w4.w;

        int cnt = d - base; if (cnt > 64) cnt = 64;
        int cnt8 = (cnt + 7) & ~7;
        for (int jj = 0; jj < cnt8; jj += 8) {
            int sj[8];
            #pragma unroll
            for (int q = 0; q < 8; ++q)
                sj[q] = __builtin_amdgcn_readlane(ms, jj + q);
            ushort4 hv[8];
            #pragma unroll
            for (int q = 0; q < 8; ++q)
                hv[q] = *(const ushort4*)(hb + (size_t)sj[q] * HCC);
            #pragma unroll
            for (int q = 0; q < 8; ++q) {
                float wx = rlf(w4.x, jj + q), wy = rlf(w4.y, jj + q);
                float wz = rlf(w4.z, jj + q), ww = rlf(w4.w, jj + q);
                float w = (head & 2) ? ((head & 1) ? ww : wz) : ((head & 1) ? wy : wx);
                acc.x = fmaf(w, b2f(hv[q].x), acc.x);
                acc.y = fmaf(w, b2f(hv[q].y), acc.y);
                acc.z = fmaf(w, b2f(hv[q].z), acc.z);
                acc.w = fmaf(w, b2f(hv[q].w), acc.w);
            }
        }
    }
    #pragma unroll
    for (int off = 32; off; off >>= 1) {
        Dv.x += __shfl_xor(Dv.x, off);
        Dv.y += __shfl_xor(Dv.y, off);
        Dv.z += __shfl_xor(Dv.z, off);
        Dv.w += __shfl_xor(Dv.w, off);
    }
    float D = (head & 2) ? ((head & 1) ? Dv.w : Dv.z) : ((head & 1) ? Dv.y : Dv.x);
    float inv = 1.0f / (D + 1e-16f);
    float4 o = make_float4(acc.x * inv, acc.y * inv, acc.z * inv, acc.w * inv);
    *(float4*)(outA + (size_t)n * HCC + lane * 4) = o;
}

// ---------------- BN stats ----------------
__global__ void stats_kernel(const float* __restrict__ agg, float* __restrict__ sum,
                             float* __restrict__ ssq) {
    int ch = threadIdx.x;
    float s = 0.f, s2 = 0.f;
    for (int r = blockIdx.x; r < NN; r += gridDim.x) {
        float v = agg[(size_t)r * HCC + ch];
        s += v;
        s2 = fmaf(v, v, s2);
    }
    atomicAdd(&sum[ch], s);
    atomicAdd(&ssq[ch], s2);
}

__global__ void bnfin_kernel(const float* __restrict__ sum, const float* __restrict__ ssq,
                             const float* __restrict__ gamma, const float* __restrict__ beta,
                             float* __restrict__ kv, float* __restrict__ cv) {
    int ch = threadIdx.x;
    const float invN = 1.0f / (float)NN;
    float mr = sum[ch] * invN;
    float var = ssq[ch] * invN - mr * mr;
    float k = gamma[ch] * rsqrtf(var + 1e-5f);
    kv[ch] = k;
    cv[ch] = beta[ch] - mr * k;
}

// ReLU(BN(agg)) -> bf16 xcur
__global__ void norm_kernel(const float* __restrict__ agg, const float* __restrict__ kv,
                            const float* __restrict__ cv, unsigned short* __restrict__ xo) {
    size_t idx = (size_t)blockIdx.x * 256 + threadIdx.x;
    size_t i = idx * 4;
    if (i >= NHC) return;
    int ch = (int)(i & 255);
    float4 v = *(const float4*)(agg + i);
    float4 k4 = *(const float4*)(kv + ch);
    float4 c4 = *(const float4*)(cv + ch);
    ushort4 o;
    o.x = f2bf(fmaxf(fmaf(v.x, k4.x, c4.x), 0.f));
    o.y = f2bf(fmaxf(fmaf(v.y, k4.y, c4.y), 0.f));
    o.z = f2bf(fmaxf(fmaf(v.z, k4.z, c4.z), 0.f));
    o.w = f2bf(fmaxf(fmaf(v.w, k4.w, c4.w), 0.f));
    *(ushort4*)(xo + i) = o;
}

// ---------------- pooling (batch sorted: run-length local accumulation) ------
__global__ void pool_kernel(const unsigned short* __restrict__ xf, const int* __restrict__ batch,
                            float* __restrict__ pool, int* __restrict__ cnt) {
    int ch = threadIdx.x;
    int nbase = blockIdx.x * 64;
    float acc = 0.f;
    int mc = 0;
    int curg = batch[nbase];
    for (int r = 0; r < 64; ++r) {
        int n = nbase + r;
        if (n >= NN) break;
        int g = batch[n];
        if (g != curg) {
            atomicAdd(&pool[(size_t)curg * HCC + ch], acc);
            if (ch == 0) atomicAdd(&cnt[curg], mc);
            acc = 0.f; mc = 0; curg = g;
        }
        acc += b2f(xf[(size_t)n * HCC + ch]);
        mc++;
    }
    atomicAdd(&pool[(size_t)curg * HCC + ch], acc);
    if (ch == 0) atomicAdd(&cnt[curg], mc);
}

__global__ void final_kernel(const float* __restrict__ pool, const int* __restrict__ cnt,
                             float* __restrict__ out) {
    int idx = blockIdx.x * 256 + threadIdx.x;
    int g = idx >> 8;
    float c = fmaxf((float)cnt[g], 1.0f);
    out[idx] = pool[idx] / c;
}

// ---------------- launch ----------------
extern "C" void kernel_launch(void* const* d_in, const int* in_sizes, int n_in,
                              void* d_out, int out_size, void* d_ws, size_t ws_size,
                              hipStream_t stream) {
    const float* x = (const float*)d_in[0];
    const int* edge_index = (const int*)d_in[1];
    const int* srcA = edge_index;
    const int* dstA = edge_index + NE;
    const float* edge_attr = (const float*)d_in[2];
    const int* batch = (const int*)d_in[3];
    const float* W[3]   = {(const float*)d_in[4],  (const float*)d_in[10], (const float*)d_in[16]};
    const float* asc[3] = {(const float*)d_in[5],  (const float*)d_in[11], (const float*)d_in[17]};
    const float* adc[3] = {(const float*)d_in[6],  (const float*)d_in[12], (const float*)d_in[18]};
    const float* gam[3] = {(const float*)d_in[8],  (const float*)d_in[14], (const float*)d_in[20]};
    const float* bet[3] = {(const float*)d_in[9],  (const float*)d_in[15], (const float*)d_in[21]};
    const float* We0 = (const float*)d_in[22];
    const float* att_e0 = (const float*)d_in[23];

    float* wsf = (float*)d_ws;
    unsigned short* hbuf = (unsigned short*)(wsf + O_H);
    unsigned short* xb   = (unsigned short*)(wsf + O_XB);
    float* aggb  = wsf + O_AGG;
    unsigned short* xcur = (unsigned short*)(wsf + O_XC);
    unsigned short* Bt   = (unsigned short*)(wsf + O_BT);
    float* aE    = wsf + O_AE;
    int*   eid   = (int*)(wsf + O_EID);
    int*   srcP  = (int*)(wsf + O_SRCP);
    int*   dstP  = (int*)(wsf + O_DSTP);
    float* alphaP= wsf + O_ALP;
    int*   startA= (int*)(wsf + O_START);
    int*   cur   = (int*)(wsf + O_CUR);
    float* asA   = wsf + O_AS;
    float* adA   = wsf + O_AD;
    float* Mb    = wsf + O_M;
    float* kv    = wsf + O_KV;
    float* cv    = wsf + O_CV;
    int*   deg   = (int*)(wsf + O_DEG);
    int*   cnt   = (int*)(wsf + O_CNT);
    int*   ctr   = (int*)(wsf + O_CTR);
    float* meanacc = wsf + O_MEAN;
    float* sums  = wsf + O_SUM;
    float* ssqs  = wsf + O_SSQ;
    float* pool  = wsf + O_POOL;

    hipMemsetAsync((void*)(wsf + O_ZERO), 0, (O_END - O_ZERO) * sizeof(float), stream);

    // CSR over dst (shared by all layers)
    deg_kernel<<<(ET + 255) / 256, 256, 0, stream>>>(dstA, deg);
    start_kernel<<<(NN + 255) / 256, 256, 0, stream>>>(deg, startA, cur, ctr);
    scatter_kernel<<<(ET + 255) / 256, 256, 0, stream>>>(srcA, dstA, cur, eid, srcP, dstP);

    // edge attention logits (layer 0 only)
    m_kernel<<<1, 64, 0, stream>>>(We0, att_e0, Mb);
    mean_kernel<<<256, 256, 0, stream>>>(edge_attr, meanacc);
    alphae_kernel<<<(ET + 255) / 256, 256, 0, stream>>>(edge_attr, Mb, meanacc, aE);

    // x -> bf16
    cvt_x_kernel<<<(NN * 128) / 1024, 256, 0, stream>>>(x, xb);

    for (int L = 0; L < 3; ++L) {
        int K = (L == 0) ? 128 : 256;
        cvt_w_kernel<<<K, 256, 0, stream>>>(W[L], Bt, K);
        if (L == 0)
            gemm_mfma<128><<<782, 256, 0, stream>>>(xb, Bt, hbuf, NN);
        else
            gemm_mfma<256><<<782, 256, 0, stream>>>(xcur, Bt, hbuf, NN);
        asad_kernel<<<12500, 256, 0, stream>>>(hbuf, asc[L], adc[L], asA, adA);
        if (L == 0)
            alphap_kernel<true><<<(ET + 255) / 256, 256, 0, stream>>>(srcP, dstP, eid, asA, adA, aE, alphaP);
        else
            alphap_kernel<false><<<(ET + 255) / 256, 256, 0, stream>>>(srcP, dstP, eid, asA, adA, aE, alphaP);
        agg_kernel<<<12500, 256, 0, stream>>>(hbuf, alphaP, srcP, startA, deg, aggb);
        stats_kernel<<<256, 256, 0, stream>>>(aggb, sums + L * 256, ssqs + L * 256);
        bnfin_kernel<<<1, 256, 0, stream>>>(sums + L * 256, ssqs + L * 256, gam[L], bet[L], kv, cv);
        norm_kernel<<<12500, 256, 0, stream>>>(aggb, kv, cv, xcur);
    }

    pool_kernel<<<782, 256, 0, stream>>>(xcur, batch, pool, cnt);
    final_kernel<<<256, 256, 0, stream>>>(pool, cnt, (float*)d_out);
}

// Round 5
// 841.231 us; speedup vs baseline: 1.6061x; 1.0760x over previous
//
#include <hip/hip_runtime.h>
#include <math.h>

#define NN 50000
#define NE 800000
#define ET 850000   // NE + NN self loops
#define HCC 256     // H*C
#define GG 256

// ---------------- workspace layout (float-element offsets) ----------------
constexpr size_t NHC    = (size_t)NN * HCC;          // 12,800,000
constexpr size_t O_H    = 0;                         // bf16 h [NN,256] (half the slot)
constexpr size_t O_XB   = O_H + NHC / 2;             // bf16 x [NN,128] (upper half of h slot)
constexpr size_t O_AGG  = O_H + NHC;
constexpr size_t O_XC   = O_AGG + NHC;               // bf16 xcur [NN,256] (half the slot)
constexpr size_t O_BT   = O_XC + NHC / 2;            // bf16 Bt [256,256] (upper half)
constexpr size_t O_AE   = O_XC + NHC;                // alphaE [ET,4] (edge-indexed)
constexpr size_t O_EID  = O_AE + (size_t)ET * 4;     // int [ET] CSR pos -> edge id
constexpr size_t O_SRCP = O_EID + ET;                // int [ET] CSR pos -> src node
constexpr size_t O_DSTP = O_SRCP + ET;               // int [ET] CSR pos -> dst node
constexpr size_t O_ALP  = O_DSTP + ET;               // [ET,4] leaky logits, CSR order
constexpr size_t O_START= O_ALP + (size_t)ET * 4;    // int [NN]
constexpr size_t O_CUR  = O_START + NN;              // int [NN]
constexpr size_t O_AS   = O_CUR + NN;                // [NN,4]
constexpr size_t O_AD   = O_AS + (size_t)NN * 4;     // [NN,4]
constexpr size_t O_M    = O_AD + (size_t)NN * 4;     // [16,4]
constexpr size_t O_KV   = O_M + 64;                  // 256
constexpr size_t O_CV   = O_KV + 256;                // 256
// ---- zero zone (single memset) ----
constexpr size_t O_ZERO = O_CV + 256;
constexpr size_t O_DEG  = O_ZERO;                    // int [NN]
constexpr size_t O_CNT  = O_DEG + NN;                // int [GG]
constexpr size_t O_CTR  = O_CNT + GG;                // int [1] (+3 pad)
constexpr size_t O_SLS  = O_CTR + 4;                 // [4] self-loop logit sum
constexpr size_t O_SUM  = O_SLS + 4;                 // [3*256]
constexpr size_t O_SSQ  = O_SUM + 768;               // [3*256]
constexpr size_t O_POOL = O_SSQ + 768;               // [GG*HCC]
constexpr size_t O_END  = O_POOL + (size_t)GG * HCC;

typedef __attribute__((ext_vector_type(8))) short bf16x8;
typedef __attribute__((ext_vector_type(4))) float f32x4;

__device__ inline float rlf(float v, int l) {
    return __int_as_float(__builtin_amdgcn_readlane(__float_as_int(v), l));
}
__device__ inline unsigned short f2bf(float f) {   // RNE
    unsigned int u = __float_as_uint(f);
    unsigned int r = (u + 0x7fffu + ((u >> 16) & 1u)) >> 16;
    return (unsigned short)r;
}
__device__ inline float b2f(unsigned short u) {
    return __uint_as_float(((unsigned int)u) << 16);
}

// ---------------- CSR build ----------------
__global__ void deg_kernel(const int* __restrict__ dstA, int* __restrict__ deg) {
    int e = blockIdx.x * 256 + threadIdx.x;
    if (e >= ET) return;
    int d = (e < NE) ? dstA[e] : (e - NE);
    atomicAdd(&deg[d], 1);
}

__global__ void start_kernel(const int* __restrict__ deg, int* __restrict__ startA,
                             int* __restrict__ cur, int* __restrict__ ctr) {
    int n = blockIdx.x * 256 + threadIdx.x;
    if (n >= NN) return;
    int v = deg[n];
    int s = atomicAdd(ctr, v);
    startA[n] = s;
    cur[n] = s;
}

__global__ void scatter_kernel(const int* __restrict__ srcA, const int* __restrict__ dstA,
                               int* __restrict__ cur, int* __restrict__ eid,
                               int* __restrict__ srcP, int* __restrict__ dstP) {
    int e = blockIdx.x * 256 + threadIdx.x;
    if (e >= ET) return;
    int d = (e < NE) ? dstA[e] : (e - NE);
    int s = (e < NE) ? srcA[e] : (e - NE);
    int p = atomicAdd(&cur[d], 1);
    eid[p] = e;
    srcP[p] = s;
    dstP[p] = d;
}

// ---------------- dtype conversion ----------------
__global__ void cvt_x_kernel(const float* __restrict__ x, unsigned short* __restrict__ xb) {
    size_t i = ((size_t)blockIdx.x * 256 + threadIdx.x) * 4;   // 6,400,000 total
    float4 v = *(const float4*)(x + i);
    ushort4 o;
    o.x = f2bf(v.x); o.y = f2bf(v.y); o.z = f2bf(v.z); o.w = f2bf(v.w);
    *(ushort4*)(xb + i) = o;
}

// W [K,256] fp32 -> Bt [256,K] bf16 (transposed)
__global__ void cvt_w_kernel(const float* __restrict__ W, unsigned short* __restrict__ Bt, int K) {
    int idx = blockIdx.x * 256 + threadIdx.x;   // K*256 threads
    int n = idx & 255, k = idx >> 8;
    Bt[(size_t)n * K + k] = f2bf(W[(size_t)k * 256 + n]);
}

// ---------------- edge-attention precompute ----------------
__global__ void m_kernel(const float* __restrict__ We0, const float* __restrict__ att_e0,
                         float* __restrict__ M) {
    int t = threadIdx.x;           // 64 threads
    int k = t >> 2, hh = t & 3;
    float s = 0.f;
    for (int c = 0; c < 64; ++c)
        s += We0[k * 256 + hh * 64 + c] * att_e0[hh * 64 + c];
    M[k * 4 + hh] = s;
}

// real edges only (NE = 3125*256 exactly); also accumulate sum of o for
// the self-loop mean (alpha_e is linear in edge_attr -> mean(attr)@M = mean(o)).
__global__ void alphae_kernel(const float* __restrict__ ea, const float* __restrict__ M,
                              float* __restrict__ aE, float* __restrict__ slsum) {
    size_t e = (size_t)blockIdx.x * 256 + threadIdx.x;
    const float4* p = (const float4*)(ea + e * 16);
    float4 a = p[0], b = p[1], c = p[2], d = p[3];
    float v[16] = {a.x, a.y, a.z, a.w, b.x, b.y, b.z, b.w,
                   c.x, c.y, c.z, c.w, d.x, d.y, d.z, d.w};
    float o[4] = {0.f, 0.f, 0.f, 0.f};
    #pragma unroll
    for (int k = 0; k < 16; ++k) {
        float4 m4 = *(const float4*)(M + k * 4);
        o[0] = fmaf(v[k], m4.x, o[0]);
        o[1] = fmaf(v[k], m4.y, o[1]);
        o[2] = fmaf(v[k], m4.z, o[2]);
        o[3] = fmaf(v[k], m4.w, o[3]);
    }
    *(float4*)(aE + e * 4) = make_float4(o[0], o[1], o[2], o[3]);
    // block-reduce o -> 4 atomics per block
    float r0 = o[0], r1 = o[1], r2 = o[2], r3 = o[3];
    #pragma unroll
    for (int off = 32; off; off >>= 1) {
        r0 += __shfl_xor(r0, off);
        r1 += __shfl_xor(r1, off);
        r2 += __shfl_xor(r2, off);
        r3 += __shfl_xor(r3, off);
    }
    __shared__ float part[4][4];
    int wave = threadIdx.x >> 6, lane = threadIdx.x & 63;
    if (lane == 0) {
        part[wave][0] = r0; part[wave][1] = r1;
        part[wave][2] = r2; part[wave][3] = r3;
    }
    __syncthreads();
    if (threadIdx.x < 4)
        atomicAdd(&slsum[threadIdx.x],
                  part[0][threadIdx.x] + part[1][threadIdx.x] +
                  part[2][threadIdx.x] + part[3][threadIdx.x]);
}

// fill self-loop aE entries with slsum/NE
__global__ void sl_kernel(const float* __restrict__ slsum, float* __restrict__ aE) {
    int n = blockIdx.x * 256 + threadIdx.x;
    if (n >= NN) return;
    const float inv = 1.0f / (float)NE;
    float4 m = make_float4(slsum[0] * inv, slsum[1] * inv, slsum[2] * inv, slsum[3] * inv);
    *(float4*)(aE + (size_t)(NE + n) * 4) = m;
}

// ---------------- per-edge leaky logits in CSR order ----------------
template <bool HAS_AE>
__global__ void alphap_kernel(const int* __restrict__ srcP, const int* __restrict__ dstP,
                              const int* __restrict__ eid, const float* __restrict__ asA,
                              const float* __restrict__ adA, const float* __restrict__ aE,
                              float* __restrict__ alphaP) {
    size_t p = (size_t)blockIdx.x * 256 + threadIdx.x;
    if (p >= ET) return;
    int s = srcP[p], d = dstP[p];
    float4 av = *(const float4*)(asA + (size_t)s * 4);
    float4 dv = *(const float4*)(adA + (size_t)d * 4);
    float4 t = make_float4(av.x + dv.x, av.y + dv.y, av.z + dv.z, av.w + dv.w);
    if (HAS_AE) {
        int e = eid[p];
        float4 e4 = *(const float4*)(aE + (size_t)e * 4);
        t.x += e4.x; t.y += e4.y; t.z += e4.z; t.w += e4.w;
    }
    t.x = (t.x > 0.f) ? t.x : 0.2f * t.x;
    t.y = (t.y > 0.f) ? t.y : 0.2f * t.y;
    t.z = (t.z > 0.f) ? t.z : 0.2f * t.z;
    t.w = (t.w > 0.f) ? t.w : 0.2f * t.w;
    *(float4*)(alphaP + p * 4) = t;
}

// ---------------- MFMA GEMM: H[M,256] = A[M,K](bf16) @ Bt[256,K](bf16)^T ----
template <int K>
__global__ __launch_bounds__(256) void gemm_mfma(const unsigned short* __restrict__ A,
                                                 const unsigned short* __restrict__ Bt,
                                                 unsigned short* __restrict__ Hout, int M) {
    __shared__ unsigned short As[64][40];    // pad 40 -> 80B row stride
    __shared__ unsigned short Bs[256][40];   // Bs[n][k] = B^T
    int tid = threadIdx.x;
    int wave = tid >> 6, lane = tid & 63;
    int quad = lane >> 4, l16 = lane & 15;
    int row0 = blockIdx.x * 64;
    f32x4 acc[4][4] = {};                    // [mi][ni]

    for (int k0 = 0; k0 < K; k0 += 32) {
        {
            int row = tid >> 2, seg = tid & 3;
            uint4 v = make_uint4(0u, 0u, 0u, 0u);
            if (row0 + row < M)
                v = *(const uint4*)(A + (size_t)(row0 + row) * K + k0 + seg * 8);
            *(uint4*)&As[row][seg * 8] = v;
        }
        {
            const uint4* src = (const uint4*)(Bt + (size_t)tid * K + k0);
            uint4 b0 = src[0], b1 = src[1], b2 = src[2], b3 = src[3];
            uint4* dst = (uint4*)&Bs[tid][0];
            dst[0] = b0; dst[1] = b1; dst[2] = b2; dst[3] = b3;
        }
        __syncthreads();
        bf16x8 a_frag[4], b_frag[4];
        #pragma unroll
        for (int mi = 0; mi < 4; ++mi)
            a_frag[mi] = *(const bf16x8*)&As[mi * 16 + l16][quad * 8];
        #pragma unroll
        for (int ni = 0; ni < 4; ++ni)
            b_frag[ni] = *(const bf16x8*)&Bs[wave * 64 + ni * 16 + l16][quad * 8];
        #pragma unroll
        for (int mi = 0; mi < 4; ++mi)
            #pragma unroll
            for (int ni = 0; ni < 4; ++ni)
                acc[mi][ni] = __builtin_amdgcn_mfma_f32_16x16x32_bf16(
                    a_frag[mi], b_frag[ni], acc[mi][ni], 0, 0, 0);
        __syncthreads();
    }

    #pragma unroll
    for (int mi = 0; mi < 4; ++mi) {
        #pragma unroll
        for (int reg = 0; reg < 4; ++reg) {
            int r = row0 + mi * 16 + quad * 4 + reg;
            if (r < M) {
                #pragma unroll
                for (int ni = 0; ni < 4; ++ni) {
                    int c = wave * 64 + ni * 16 + l16;
                    Hout[(size_t)r * HCC + c] = f2bf(acc[mi][ni][reg]);
                }
            }
        }
    }
}

// ---------------- per-node attention logits (bf16 h) ----------------
__global__ void asad_kernel(const unsigned short* __restrict__ Hm,
                            const float* __restrict__ att_src,
                            const float* __restrict__ att_dst, float* __restrict__ asA,
                            float* __restrict__ adA) {
    int wave = threadIdx.x >> 6, lane = threadIdx.x & 63;
    int n = blockIdx.x * 4 + wave;
    if (n >= NN) return;
    int head = lane >> 4;
    int ci = (lane & 15) * 4;
    ushort4 hv4 = *(const ushort4*)(Hm + (size_t)n * HCC + lane * 4);
    float hx = b2f(hv4.x), hy = b2f(hv4.y), hz = b2f(hv4.z), hw = b2f(hv4.w);
    float4 s4 = *(const float4*)(att_src + head * 64 + ci);
    float4 d4 = *(const float4*)(att_dst + head * 64 + ci);
    float ps = hx * s4.x + hy * s4.y + hz * s4.z + hw * s4.w;
    float pd = hx * d4.x + hy * d4.y + hz * d4.z + hw * d4.w;
    #pragma unroll
    for (int off = 8; off; off >>= 1) {
        ps += __shfl_xor(ps, off);
        pd += __shfl_xor(pd, off);
    }
    if ((lane & 15) == 0) {
        asA[n * 4 + head] = ps;
        adA[n * 4 + head] = pd;
    }
}

// ---------------- per-node softmax aggregation (wave per node, CSR-ordered) --
__global__ __launch_bounds__(256) void agg_kernel(const unsigned short* __restrict__ Hm,
                                                  const float* __restrict__ alphaP,
                                                  const int* __restrict__ srcP,
                                                  const int* __restrict__ startA,
                                                  const int* __restrict__ degA,
                                                  float* __restrict__ outA) {
    int wave = threadIdx.x >> 6, lane = threadIdx.x & 63;
    int n = blockIdx.x * 4 + wave;
    if (n >= NN) return;
    int head = lane >> 4;
    int st = startA[n];
    int d = degA[n];

    float4 m4 = make_float4(-1e30f, -1e30f, -1e30f, -1e30f);
    for (int j = lane; j < d; j += 64) {
        float4 a = *(const float4*)(alphaP + (size_t)(st + j) * 4);
        m4.x = fmaxf(m4.x, a.x); m4.y = fmaxf(m4.y, a.y);
        m4.z = fmaxf(m4.z, a.z); m4.w = fmaxf(m4.w, a.w);
    }
    #pragma unroll
    for (int off = 32; off; off >>= 1) {
        m4.x = fmaxf(m4.x, __shfl_xor(m4.x, off));
        m4.y = fmaxf(m4.y, __shfl_xor(m4.y, off));
        m4.z = fmaxf(m4.z, __shfl_xor(m4.z, off));
        m4.w = fmaxf(m4.w, __shfl_xor(m4.w, off));
    }

    float4 Dv = make_float4(0.f, 0.f, 0.f, 0.f);
    float4 acc = make_float4(0.f, 0.f, 0.f, 0.f);
    const unsigned short* hb = Hm + lane * 4;
    for (int base = 0; base < d; base += 64) {
        int j = base + lane;
        float4 a4 = make_float4(-1e30f, -1e30f, -1e30f, -1e30f);
        int ms = 0;
        if (j < d) {
            a4 = *(const float4*)(alphaP + (size_t)(st + j) * 4);
            ms = srcP[st + j];
        }
        float4 w4;
        w4.x = __expf(a4.x - m4.x);
        w4.y = __expf(a4.y - m4.y);
        w4.z = __expf(a4.z - m4.z);
        w4.w = __expf(a4.w - m4.w);
        Dv.x += w4.x; Dv.y += w4.y; Dv.z += w4.z; Dv.w += w4.w;

        int cnt = d - base; if (cnt > 64) cnt = 64;
        int cnt8 = (cnt + 7) & ~7;
        for (int jj = 0; jj < cnt8; jj += 8) {
            int sj[8];
            #pragma unroll
            for (int q = 0; q < 8; ++q)
                sj[q] = __builtin_amdgcn_readlane(ms, jj + q);
            ushort4 hv[8];
            #pragma unroll
            for (int q = 0; q < 8; ++q)
                hv[q] = *(const ushort4*)(hb + (size_t)sj[q] * HCC);
            #pragma unroll
            for (int q = 0; q < 8; ++q) {
                float wx = rlf(w4.x, jj + q), wy = rlf(w4.y, jj + q);
                float wz = rlf(w4.z, jj + q), ww = rlf(w4.w, jj + q);
                float w = (head & 2) ? ((head & 1) ? ww : wz) : ((head & 1) ? wy : wx);
                acc.x = fmaf(w, b2f(hv[q].x), acc.x);
                acc.y = fmaf(w, b2f(hv[q].y), acc.y);
                acc.z = fmaf(w, b2f(hv[q].z), acc.z);
                acc.w = fmaf(w, b2f(hv[q].w), acc.w);
            }
        }
    }
    #pragma unroll
    for (int off = 32; off; off >>= 1) {
        Dv.x += __shfl_xor(Dv.x, off);
        Dv.y += __shfl_xor(Dv.y, off);
        Dv.z += __shfl_xor(Dv.z, off);
        Dv.w += __shfl_xor(Dv.w, off);
    }
    float D = (head & 2) ? ((head & 1) ? Dv.w : Dv.z) : ((head & 1) ? Dv.y : Dv.x);
    float inv = 1.0f / (D + 1e-16f);
    float4 o = make_float4(acc.x * inv, acc.y * inv, acc.z * inv, acc.w * inv);
    *(float4*)(outA + (size_t)n * HCC + lane * 4) = o;
}

// ---------------- BN stats ----------------
__global__ void stats_kernel(const float* __restrict__ agg, float* __restrict__ sum,
                             float* __restrict__ ssq) {
    int ch = threadIdx.x;
    float s = 0.f, s2 = 0.f;
    for (int r = blockIdx.x; r < NN; r += gridDim.x) {
        float v = agg[(size_t)r * HCC + ch];
        s += v;
        s2 = fmaf(v, v, s2);
    }
    atomicAdd(&sum[ch], s);
    atomicAdd(&ssq[ch], s2);
}

__global__ void bnfin_kernel(const float* __restrict__ sum, const float* __restrict__ ssq,
                             const float* __restrict__ gamma, const float* __restrict__ beta,
                             float* __restrict__ kv, float* __restrict__ cv) {
    int ch = threadIdx.x;
    const float invN = 1.0f / (float)NN;
    float mr = sum[ch] * invN;
    float var = ssq[ch] * invN - mr * mr;
    float k = gamma[ch] * rsqrtf(var + 1e-5f);
    kv[ch] = k;
    cv[ch] = beta[ch] - mr * k;
}

// ReLU(BN(agg)) -> bf16 xcur
__global__ void norm_kernel(const float* __restrict__ agg, const float* __restrict__ kv,
                            const float* __restrict__ cv, unsigned short* __restrict__ xo) {
    size_t idx = (size_t)blockIdx.x * 256 + threadIdx.x;
    size_t i = idx * 4;
    if (i >= NHC) return;
    int ch = (int)(i & 255);
    float4 v = *(const float4*)(agg + i);
    float4 k4 = *(const float4*)(kv + ch);
    float4 c4 = *(const float4*)(cv + ch);
    ushort4 o;
    o.x = f2bf(fmaxf(fmaf(v.x, k4.x, c4.x), 0.f));
    o.y = f2bf(fmaxf(fmaf(v.y, k4.y, c4.y), 0.f));
    o.z = f2bf(fmaxf(fmaf(v.z, k4.z, c4.z), 0.f));
    o.w = f2bf(fmaxf(fmaf(v.w, k4.w, c4.w), 0.f));
    *(ushort4*)(xo + i) = o;
}

// ---------------- pooling (batch sorted: run-length local accumulation) ------
__global__ void pool_kernel(const unsigned short* __restrict__ xf, const int* __restrict__ batch,
                            float* __restrict__ pool, int* __restrict__ cnt) {
    int ch = threadIdx.x;
    int nbase = blockIdx.x * 64;
    float acc = 0.f;
    int mc = 0;
    int curg = batch[nbase];
    for (int r = 0; r < 64; ++r) {
        int n = nbase + r;
        if (n >= NN) break;
        int g = batch[n];
        if (g != curg) {
            atomicAdd(&pool[(size_t)curg * HCC + ch], acc);
            if (ch == 0) atomicAdd(&cnt[curg], mc);
            acc = 0.f; mc = 0; curg = g;
        }
        acc += b2f(xf[(size_t)n * HCC + ch]);
        mc++;
    }
    atomicAdd(&pool[(size_t)curg * HCC + ch], acc);
    if (ch == 0) atomicAdd(&cnt[curg], mc);
}

__global__ void final_kernel(const float* __restrict__ pool, const int* __restrict__ cnt,
                             float* __restrict__ out) {
    int idx = blockIdx.x * 256 + threadIdx.x;
    int g = idx >> 8;
    float c = fmaxf((float)cnt[g], 1.0f);
    out[idx] = pool[idx] / c;
}

// ---------------- launch ----------------
extern "C" void kernel_launch(void* const* d_in, const int* in_sizes, int n_in,
                              void* d_out, int out_size, void* d_ws, size_t ws_size,
                              hipStream_t stream) {
    const float* x = (const float*)d_in[0];
    const int* edge_index = (const int*)d_in[1];
    const int* srcA = edge_index;
    const int* dstA = edge_index + NE;
    const float* edge_attr = (const float*)d_in[2];
    const int* batch = (const int*)d_in[3];
    const float* W[3]   = {(const float*)d_in[4],  (const float*)d_in[10], (const float*)d_in[16]};
    const float* asc[3] = {(const float*)d_in[5],  (const float*)d_in[11], (const float*)d_in[17]};
    const float* adc[3] = {(const float*)d_in[6],  (const float*)d_in[12], (const float*)d_in[18]};
    const float* gam[3] = {(const float*)d_in[8],  (const float*)d_in[14], (const float*)d_in[20]};
    const float* bet[3] = {(const float*)d_in[9],  (const float*)d_in[15], (const float*)d_in[21]};
    const float* We0 = (const float*)d_in[22];
    const float* att_e0 = (const float*)d_in[23];

    float* wsf = (float*)d_ws;
    unsigned short* hbuf = (unsigned short*)(wsf + O_H);
    unsigned short* xb   = (unsigned short*)(wsf + O_XB);
    float* aggb  = wsf + O_AGG;
    unsigned short* xcur = (unsigned short*)(wsf + O_XC);
    unsigned short* Bt   = (unsigned short*)(wsf + O_BT);
    float* aE    = wsf + O_AE;
    int*   eid   = (int*)(wsf + O_EID);
    int*   srcP  = (int*)(wsf + O_SRCP);
    int*   dstP  = (int*)(wsf + O_DSTP);
    float* alphaP= wsf + O_ALP;
    int*   startA= (int*)(wsf + O_START);
    int*   cur   = (int*)(wsf + O_CUR);
    float* asA   = wsf + O_AS;
    float* adA   = wsf + O_AD;
    float* Mb    = wsf + O_M;
    float* kv    = wsf + O_KV;
    float* cv    = wsf + O_CV;
    int*   deg   = (int*)(wsf + O_DEG);
    int*   cnt   = (int*)(wsf + O_CNT);
    int*   ctr   = (int*)(wsf + O_CTR);
    float* slsum = wsf + O_SLS;
    float* sums  = wsf + O_SUM;
    float* ssqs  = wsf + O_SSQ;
    float* pool  = wsf + O_POOL;

    hipMemsetAsync((void*)(wsf + O_ZERO), 0, (O_END - O_ZERO) * sizeof(float), stream);

    // CSR over dst (shared by all layers)
    deg_kernel<<<(ET + 255) / 256, 256, 0, stream>>>(dstA, deg);
    start_kernel<<<(NN + 255) / 256, 256, 0, stream>>>(deg, startA, cur, ctr);
    scatter_kernel<<<(ET + 255) / 256, 256, 0, stream>>>(srcA, dstA, cur, eid, srcP, dstP);

    // edge attention logits (layer 0 only); self-loop via linearity
    m_kernel<<<1, 64, 0, stream>>>(We0, att_e0, Mb);
    alphae_kernel<<<NE / 256, 256, 0, stream>>>(edge_attr, Mb, aE, slsum);
    sl_kernel<<<(NN + 255) / 256, 256, 0, stream>>>(slsum, aE);

    // x -> bf16
    cvt_x_kernel<<<(NN * 128) / 1024, 256, 0, stream>>>(x, xb);

    for (int L = 0; L < 3; ++L) {
        int K = (L == 0) ? 128 : 256;
        cvt_w_kernel<<<K, 256, 0, stream>>>(W[L], Bt, K);
        if (L == 0)
            gemm_mfma<128><<<782, 256, 0, stream>>>(xb, Bt, hbuf, NN);
        else
            gemm_mfma<256><<<782, 256, 0, stream>>>(xcur, Bt, hbuf, NN);
        asad_kernel<<<12500, 256, 0, stream>>>(hbuf, asc[L], adc[L], asA, adA);
        if (L == 0)
            alphap_kernel<true><<<(ET + 255) / 256, 256, 0, stream>>>(srcP, dstP, eid, asA, adA, aE, alphaP);
        else
            alphap_kernel<false><<<(ET + 255) / 256, 256, 0, stream>>>(srcP, dstP, eid, asA, adA, aE, alphaP);
        agg_kernel<<<12500, 256, 0, stream>>>(hbuf, alphaP, srcP, startA, deg, aggb);
        stats_kernel<<<1024, 256, 0, stream>>>(aggb, sums + L * 256, ssqs + L * 256);
        bnfin_kernel<<<1, 256, 0, stream>>>(sums + L * 256, ssqs + L * 256, gam[L], bet[L], kv, cv);
        norm_kernel<<<12500, 256, 0, stream>>>(aggb, kv, cv, xcur);
    }

    pool_kernel<<<782, 256, 0, stream>>>(xcur, batch, pool, cnt);
    final_kernel<<<256, 256, 0, stream>>>(pool, cnt, (float*)d_out);
}

// Round 6
// 780.243 us; speedup vs baseline: 1.7316x; 1.0782x over previous
//
#include <hip/hip_runtime.h>
#include <math.h>

#define NN 50000
#define NE 800000
#define ET 850000   // NE + NN self loops
#define HCC 256     // H*C
#define GG 256

// ---------------- workspace layout (float-element offsets) ----------------
constexpr size_t NHC    = (size_t)NN * HCC;          // 12,800,000
constexpr size_t O_H    = 0;                         // bf16 h [NN,256] (half the slot)
constexpr size_t O_AGG  = O_H + NHC;                 // fp32 agg [NN,256]
constexpr size_t O_XC   = O_AGG + NHC;               // (unused)
constexpr size_t O_BT   = O_XC + NHC / 2;            // bf16 Bt [256,256]
constexpr size_t O_AE   = O_XC + NHC;                // (unused, old edge-indexed aE)
constexpr size_t O_POS  = O_AE + (size_t)ET * 4;     // int [ET] edge id -> CSR pos
constexpr size_t O_SRCP = O_POS + ET;                // int [ET] CSR pos -> src node
constexpr size_t O_DSTP = O_SRCP + ET;               // (unused)
constexpr size_t O_AEP  = O_DSTP + ET;               // [ET,4] edge logits, CSR order
constexpr size_t O_START= O_AEP + (size_t)ET * 4;    // int [NN]
constexpr size_t O_CUR  = O_START + NN;              // int [NN]
constexpr size_t O_AS   = O_CUR + NN;                // [NN,4]
constexpr size_t O_AD   = O_AS + (size_t)NN * 4;     // [NN,4]
constexpr size_t O_M    = O_AD + (size_t)NN * 4;     // [16,4]
constexpr size_t O_KV   = O_M + 64;                  // 256
constexpr size_t O_CV   = O_KV + 256;                // 256
// ---- zero zone (single memset) ----
constexpr size_t O_ZERO = O_CV + 256;
constexpr size_t O_DEG  = O_ZERO;                    // int [NN]
constexpr size_t O_CNT  = O_DEG + NN;                // int [GG]
constexpr size_t O_CTR  = O_CNT + GG;                // int [1] (+3 pad)
constexpr size_t O_SLS  = O_CTR + 4;                 // [4] self-loop logit sum
constexpr size_t O_SUM  = O_SLS + 4;                 // [3*256]
constexpr size_t O_SSQ  = O_SUM + 768;               // [3*256]
constexpr size_t O_POOL = O_SSQ + 768;               // [GG*HCC]
constexpr size_t O_END  = O_POOL + (size_t)GG * HCC;

typedef __attribute__((ext_vector_type(8))) short bf16x8;
typedef __attribute__((ext_vector_type(4))) float f32x4;

__device__ inline unsigned short f2bf(float f) {   // RNE
    unsigned int u = __float_as_uint(f);
    unsigned int r = (u + 0x7fffu + ((u >> 16) & 1u)) >> 16;
    return (unsigned short)r;
}
__device__ inline float b2f(unsigned short u) {
    return __uint_as_float(((unsigned int)u) << 16);
}

// ---------------- CSR build ----------------
__global__ void deg_kernel(const int* __restrict__ dstA, int* __restrict__ deg) {
    int e = blockIdx.x * 256 + threadIdx.x;
    if (e >= ET) return;
    int d = (e < NE) ? dstA[e] : (e - NE);
    atomicAdd(&deg[d], 1);
}

__global__ void start_kernel(const int* __restrict__ deg, int* __restrict__ startA,
                             int* __restrict__ cur, int* __restrict__ ctr) {
    int n = blockIdx.x * 256 + threadIdx.x;
    if (n >= NN) return;
    int v = deg[n];
    int s = atomicAdd(ctr, v);
    startA[n] = s;
    cur[n] = s;
}

__global__ void scatter_kernel(const int* __restrict__ srcA, const int* __restrict__ dstA,
                               int* __restrict__ cur, int* __restrict__ pos,
                               int* __restrict__ srcP) {
    int e = blockIdx.x * 256 + threadIdx.x;
    if (e >= ET) return;
    int d = (e < NE) ? dstA[e] : (e - NE);
    int s = (e < NE) ? srcA[e] : (e - NE);
    int p = atomicAdd(&cur[d], 1);
    pos[e] = p;
    srcP[p] = s;
}

// ---------------- edge-attention precompute ----------------
// M[k][h] = sum_c We0[k, h*64+c] * att_e0[h, c]
__global__ void m_kernel(const float* __restrict__ We0, const float* __restrict__ att_e0,
                         float* __restrict__ M) {
    int t = threadIdx.x;           // 64 threads
    int k = t >> 2, hh = t & 3;
    float s = 0.f;
    for (int c = 0; c < 64; ++c)
        s += We0[k * 256 + hh * 64 + c] * att_e0[hh * 64 + c];
    M[k * 4 + hh] = s;
}

// real edges (NE = 3125*256 exactly); write logits to CSR position; also
// accumulate sum for the self-loop mean (alpha_e linear in edge_attr).
__global__ void alphae_kernel(const float* __restrict__ ea, const float* __restrict__ M,
                              const int* __restrict__ pos,
                              float* __restrict__ aeP, float* __restrict__ slsum) {
    size_t e = (size_t)blockIdx.x * 256 + threadIdx.x;
    const float4* p = (const float4*)(ea + e * 16);
    float4 a = p[0], b = p[1], c = p[2], d = p[3];
    float v[16] = {a.x, a.y, a.z, a.w, b.x, b.y, b.z, b.w,
                   c.x, c.y, c.z, c.w, d.x, d.y, d.z, d.w};
    float o[4] = {0.f, 0.f, 0.f, 0.f};
    #pragma unroll
    for (int k = 0; k < 16; ++k) {
        float4 m4 = *(const float4*)(M + k * 4);
        o[0] = fmaf(v[k], m4.x, o[0]);
        o[1] = fmaf(v[k], m4.y, o[1]);
        o[2] = fmaf(v[k], m4.z, o[2]);
        o[3] = fmaf(v[k], m4.w, o[3]);
    }
    int pp = pos[e];
    *(float4*)(aeP + (size_t)pp * 4) = make_float4(o[0], o[1], o[2], o[3]);
    // block-reduce o -> 4 atomics per block
    float r0 = o[0], r1 = o[1], r2 = o[2], r3 = o[3];
    #pragma unroll
    for (int off = 32; off; off >>= 1) {
        r0 += __shfl_xor(r0, off);
        r1 += __shfl_xor(r1, off);
        r2 += __shfl_xor(r2, off);
        r3 += __shfl_xor(r3, off);
    }
    __shared__ float part[4][4];
    int wave = threadIdx.x >> 6, lane = threadIdx.x & 63;
    if (lane == 0) {
        part[wave][0] = r0; part[wave][1] = r1;
        part[wave][2] = r2; part[wave][3] = r3;
    }
    __syncthreads();
    if (threadIdx.x < 4)
        atomicAdd(&slsum[threadIdx.x],
                  part[0][threadIdx.x] + part[1][threadIdx.x] +
                  part[2][threadIdx.x] + part[3][threadIdx.x]);
}

// fill self-loop aeP entries with slsum/NE
__global__ void sl_kernel(const float* __restrict__ slsum, const int* __restrict__ pos,
                          float* __restrict__ aeP) {
    int n = blockIdx.x * 256 + threadIdx.x;
    if (n >= NN) return;
    const float inv = 1.0f / (float)NE;
    float4 m = make_float4(slsum[0] * inv, slsum[1] * inv, slsum[2] * inv, slsum[3] * inv);
    int pp = pos[NE + n];
    *(float4*)(aeP + (size_t)pp * 4) = m;
}

// W [K,256] fp32 -> Bt [256,K] bf16 (transposed)
__global__ void cvt_w_kernel(const float* __restrict__ W, unsigned short* __restrict__ Bt, int K) {
    int idx = blockIdx.x * 256 + threadIdx.x;   // K*256 threads
    int n = idx & 255, k = idx >> 8;
    Bt[(size_t)n * K + k] = f2bf(W[(size_t)k * 256 + n]);
}

// ---------------- fused GEMM: H = norm?(A) @ Bt^T, + per-head att dots ------
// A fp32 [M,K]. NORM: apply x*kv+cv, relu during staging (prev layer's BN).
// Epilogue: H bf16; asA/adA[n][h] = sum_c h[n][h*64+c]*att_{src,dst}[h][c]
// (wave w owns exactly head w's 64 channels).
template <int K, bool NORM>
__global__ __launch_bounds__(256) void gemm_fused(const float* __restrict__ A,
                                                  const unsigned short* __restrict__ Bt,
                                                  const float* __restrict__ kvv,
                                                  const float* __restrict__ cvv,
                                                  const float* __restrict__ att_src,
                                                  const float* __restrict__ att_dst,
                                                  unsigned short* __restrict__ Hout,
                                                  float* __restrict__ asA,
                                                  float* __restrict__ adA, int M) {
    __shared__ unsigned short As[64][40];    // pad 40 -> 80B row stride
    __shared__ unsigned short Bs[256][40];
    int tid = threadIdx.x;
    int wave = tid >> 6, lane = tid & 63;
    int quad = lane >> 4, l16 = lane & 15;
    int row0 = blockIdx.x * 64;
    f32x4 acc[4][4] = {};                    // [mi][ni]

    for (int k0 = 0; k0 < K; k0 += 32) {
        // stage A: 64 rows x 32 k; thread -> row tid>>2, 8-ch segment tid&3
        {
            int row = tid >> 2, seg = tid & 3;
            ushort4 o0 = make_ushort4(0, 0, 0, 0), o1 = o0;
            if (row0 + row < M) {
                const float* ap = A + (size_t)(row0 + row) * K + k0 + seg * 8;
                float4 u = *(const float4*)ap;
                float4 v2 = *(const float4*)(ap + 4);
                if (NORM) {
                    const float* kp = kvv + k0 + seg * 8;
                    const float* cp = cvv + k0 + seg * 8;
                    float4 k1 = *(const float4*)kp, k2 = *(const float4*)(kp + 4);
                    float4 c1 = *(const float4*)cp, c2 = *(const float4*)(cp + 4);
                    u.x = fmaxf(fmaf(u.x, k1.x, c1.x), 0.f);
                    u.y = fmaxf(fmaf(u.y, k1.y, c1.y), 0.f);
                    u.z = fmaxf(fmaf(u.z, k1.z, c1.z), 0.f);
                    u.w = fmaxf(fmaf(u.w, k1.w, c1.w), 0.f);
                    v2.x = fmaxf(fmaf(v2.x, k2.x, c2.x), 0.f);
                    v2.y = fmaxf(fmaf(v2.y, k2.y, c2.y), 0.f);
                    v2.z = fmaxf(fmaf(v2.z, k2.z, c2.z), 0.f);
                    v2.w = fmaxf(fmaf(v2.w, k2.w, c2.w), 0.f);
                }
                o0 = make_ushort4(f2bf(u.x), f2bf(u.y), f2bf(u.z), f2bf(u.w));
                o1 = make_ushort4(f2bf(v2.x), f2bf(v2.y), f2bf(v2.z), f2bf(v2.w));
            }
            *(ushort4*)&As[row][seg * 8] = o0;
            *(ushort4*)&As[row][seg * 8 + 4] = o1;
        }
        // stage B^T: 256 cols x 32 k; thread -> col tid (64B)
        {
            const uint4* src = (const uint4*)(Bt + (size_t)tid * K + k0);
            uint4 b0 = src[0], b1 = src[1], b2 = src[2], b3 = src[3];
            uint4* dst = (uint4*)&Bs[tid][0];
            dst[0] = b0; dst[1] = b1; dst[2] = b2; dst[3] = b3;
        }
        __syncthreads();
        bf16x8 a_frag[4], b_frag[4];
        #pragma unroll
        for (int mi = 0; mi < 4; ++mi)
            a_frag[mi] = *(const bf16x8*)&As[mi * 16 + l16][quad * 8];
        #pragma unroll
        for (int ni = 0; ni < 4; ++ni)
            b_frag[ni] = *(const bf16x8*)&Bs[wave * 64 + ni * 16 + l16][quad * 8];
        #pragma unroll
        for (int mi = 0; mi < 4; ++mi)
            #pragma unroll
            for (int ni = 0; ni < 4; ++ni)
                acc[mi][ni] = __builtin_amdgcn_mfma_f32_16x16x32_bf16(
                    a_frag[mi], b_frag[ni], acc[mi][ni], 0, 0, 0);
        __syncthreads();
    }

    // epilogue 1: H bf16 (C/D layout: col=lane&15, row=quad*4+reg)
    #pragma unroll
    for (int mi = 0; mi < 4; ++mi) {
        #pragma unroll
        for (int reg = 0; reg < 4; ++reg) {
            int r = row0 + mi * 16 + quad * 4 + reg;
            if (r < M) {
                #pragma unroll
                for (int ni = 0; ni < 4; ++ni) {
                    int c = wave * 64 + ni * 16 + l16;
                    Hout[(size_t)r * HCC + c] = f2bf(acc[mi][ni][reg]);
                }
            }
        }
    }
    // epilogue 2: per-head attention dots (head = wave)
    float asc[4], adc_[4];
    #pragma unroll
    for (int ni = 0; ni < 4; ++ni) {
        asc[ni] = att_src[wave * 64 + ni * 16 + l16];
        adc_[ni] = att_dst[wave * 64 + ni * 16 + l16];
    }
    #pragma unroll
    for (int mi = 0; mi < 4; ++mi) {
        #pragma unroll
        for (int reg = 0; reg < 4; ++reg) {
            float s1 = acc[mi][0][reg] * asc[0] + acc[mi][1][reg] * asc[1] +
                       acc[mi][2][reg] * asc[2] + acc[mi][3][reg] * asc[3];
            float d1 = acc[mi][0][reg] * adc_[0] + acc[mi][1][reg] * adc_[1] +
                       acc[mi][2][reg] * adc_[2] + acc[mi][3][reg] * adc_[3];
            #pragma unroll
            for (int off = 1; off < 16; off <<= 1) {
                s1 += __shfl_xor(s1, off);
                d1 += __shfl_xor(d1, off);
            }
            int r = row0 + mi * 16 + quad * 4 + reg;
            if (l16 == 0 && r < M) {
                asA[(size_t)r * 4 + wave] = s1;
                adA[(size_t)r * 4 + wave] = d1;
            }
        }
    }
}

// ---------------- fused softmax aggregation (wave per node, CSR) ------------
// Computes leaky logits inline (asA gather), softmax, weighted h gather-sum.
template <bool HAS_AE>
__global__ __launch_bounds__(256) void agg_kernel(const unsigned short* __restrict__ Hm,
                                                  const float* __restrict__ asA,
                                                  const float* __restrict__ adA,
                                                  const float* __restrict__ aeP,
                                                  const int* __restrict__ srcP,
                                                  const int* __restrict__ startA,
                                                  const int* __restrict__ degA,
                                                  float* __restrict__ outA) {
    __shared__ float wlds[4][260];   // [wave][head*65 + j] padded: conflict-free
    int wave = threadIdx.x >> 6, lane = threadIdx.x & 63;
    int n = blockIdx.x * 4 + wave;
    if (n >= NN) return;
    int head = lane >> 4;
    int st = startA[n];
    int d = degA[n];
    float4 ad4 = *(const float4*)(adA + (size_t)n * 4);

    // chunk-0 logits, kept in registers (deg <= 64 in practice)
    int ms = 0;
    float4 a4 = make_float4(-1e30f, -1e30f, -1e30f, -1e30f);
    if (lane < d) {
        int p = st + lane;
        ms = srcP[p];
        float4 av = *(const float4*)(asA + (size_t)ms * 4);
        float4 t = make_float4(av.x + ad4.x, av.y + ad4.y, av.z + ad4.z, av.w + ad4.w);
        if (HAS_AE) {
            float4 e4 = *(const float4*)(aeP + (size_t)p * 4);
            t.x += e4.x; t.y += e4.y; t.z += e4.z; t.w += e4.w;
        }
        a4.x = (t.x > 0.f) ? t.x : 0.2f * t.x;
        a4.y = (t.y > 0.f) ? t.y : 0.2f * t.y;
        a4.z = (t.z > 0.f) ? t.z : 0.2f * t.z;
        a4.w = (t.w > 0.f) ? t.w : 0.2f * t.w;
    }
    float4 m4 = a4;
    for (int base = 64; base < d; base += 64) {      // rare slow path
        int j = base + lane;
        if (j < d) {
            int p = st + j;
            int s2 = srcP[p];
            float4 av = *(const float4*)(asA + (size_t)s2 * 4);
            float4 t = make_float4(av.x + ad4.x, av.y + ad4.y, av.z + ad4.z, av.w + ad4.w);
            if (HAS_AE) {
                float4 e4 = *(const float4*)(aeP + (size_t)p * 4);
                t.x += e4.x; t.y += e4.y; t.z += e4.z; t.w += e4.w;
            }
            t.x = (t.x > 0.f) ? t.x : 0.2f * t.x;
            t.y = (t.y > 0.f) ? t.y : 0.2f * t.y;
            t.z = (t.z > 0.f) ? t.z : 0.2f * t.z;
            t.w = (t.w > 0.f) ? t.w : 0.2f * t.w;
            m4.x = fmaxf(m4.x, t.x); m4.y = fmaxf(m4.y, t.y);
            m4.z = fmaxf(m4.z, t.z); m4.w = fmaxf(m4.w, t.w);
        }
    }
    #pragma unroll
    for (int off = 32; off; off >>= 1) {
        m4.x = fmaxf(m4.x, __shfl_xor(m4.x, off));
        m4.y = fmaxf(m4.y, __shfl_xor(m4.y, off));
        m4.z = fmaxf(m4.z, __shfl_xor(m4.z, off));
        m4.w = fmaxf(m4.w, __shfl_xor(m4.w, off));
    }

    float4 Dv = make_float4(0.f, 0.f, 0.f, 0.f);
    float4 acc = make_float4(0.f, 0.f, 0.f, 0.f);
    const unsigned short* hb = Hm + lane * 4;
    for (int base = 0; base < d; base += 64) {
        float4 a4c;
        int msc;
        if (base == 0) {
            a4c = a4; msc = ms;
        } else {                                     // rare: recompute logits
            a4c = make_float4(-1e30f, -1e30f, -1e30f, -1e30f);
            msc = 0;
            int j = base + lane;
            if (j < d) {
                int p = st + j;
                msc = srcP[p];
                float4 av = *(const float4*)(asA + (size_t)msc * 4);
                float4 t = make_float4(av.x + ad4.x, av.y + ad4.y, av.z + ad4.z, av.w + ad4.w);
                if (HAS_AE) {
                    float4 e4 = *(const float4*)(aeP + (size_t)p * 4);
                    t.x += e4.x; t.y += e4.y; t.z += e4.z; t.w += e4.w;
                }
                a4c.x = (t.x > 0.f) ? t.x : 0.2f * t.x;
                a4c.y = (t.y > 0.f) ? t.y : 0.2f * t.y;
                a4c.z = (t.z > 0.f) ? t.z : 0.2f * t.z;
                a4c.w = (t.w > 0.f) ? t.w : 0.2f * t.w;
            }
        }
        float4 w4;
        w4.x = __expf(a4c.x - m4.x);    // 0 for padded lanes
        w4.y = __expf(a4c.y - m4.y);
        w4.z = __expf(a4c.z - m4.z);
        w4.w = __expf(a4c.w - m4.w);
        Dv.x += w4.x; Dv.y += w4.y; Dv.z += w4.z; Dv.w += w4.w;
        // stash weights: wlds[wave][h*65 + j]
        wlds[wave][0 * 65 + lane] = w4.x;
        wlds[wave][1 * 65 + lane] = w4.y;
        wlds[wave][2 * 65 + lane] = w4.z;
        wlds[wave][3 * 65 + lane] = w4.w;

        int cnt = d - base; if (cnt > 64) cnt = 64;
        int cnt8 = (cnt + 7) & ~7;                   // padded lanes have w=0
        const float* wrow = &wlds[wave][head * 65];
        for (int jj = 0; jj < cnt8; jj += 8) {
            int sj[8];
            #pragma unroll
            for (int q = 0; q < 8; ++q)
                sj[q] = __builtin_amdgcn_readlane(msc, jj + q);
            ushort4 hv[8];
            #pragma unroll
            for (int q = 0; q < 8; ++q)
                hv[q] = *(const ushort4*)(hb + (size_t)sj[q] * HCC);
            float wq[8];
            #pragma unroll
            for (int q = 0; q < 8; ++q)
                wq[q] = wrow[jj + q];                // LDS broadcast per head
            #pragma unroll
            for (int q = 0; q < 8; ++q) {
                acc.x = fmaf(wq[q], b2f(hv[q].x), acc.x);
                acc.y = fmaf(wq[q], b2f(hv[q].y), acc.y);
                acc.z = fmaf(wq[q], b2f(hv[q].z), acc.z);
                acc.w = fmaf(wq[q], b2f(hv[q].w), acc.w);
            }
        }
    }
    #pragma unroll
    for (int off = 32; off; off >>= 1) {
        Dv.x += __shfl_xor(Dv.x, off);
        Dv.y += __shfl_xor(Dv.y, off);
        Dv.z += __shfl_xor(Dv.z, off);
        Dv.w += __shfl_xor(Dv.w, off);
    }
    float D = (head & 2) ? ((head & 1) ? Dv.w : Dv.z) : ((head & 1) ? Dv.y : Dv.x);
    float inv = 1.0f / (D + 1e-16f);
    float4 o = make_float4(acc.x * inv, acc.y * inv, acc.z * inv, acc.w * inv);
    *(float4*)(outA + (size_t)n * HCC + lane * 4) = o;
}

// ---------------- BN stats ----------------
__global__ void stats_kernel(const float* __restrict__ agg, float* __restrict__ sum,
                             float* __restrict__ ssq) {
    int ch = threadIdx.x;
    float s = 0.f, s2 = 0.f;
    for (int r = blockIdx.x; r < NN; r += gridDim.x) {
        float v = agg[(size_t)r * HCC + ch];
        s += v;
        s2 = fmaf(v, v, s2);
    }
    atomicAdd(&sum[ch], s);
    atomicAdd(&ssq[ch], s2);
}

// bias cancels under batch-stat BN: normalized = agg*k + c
__global__ void bnfin_kernel(const float* __restrict__ sum, const float* __restrict__ ssq,
                             const float* __restrict__ gamma, const float* __restrict__ beta,
                             float* __restrict__ kv, float* __restrict__ cv) {
    int ch = threadIdx.x;
    const float invN = 1.0f / (float)NN;
    float mr = sum[ch] * invN;
    float var = ssq[ch] * invN - mr * mr;
    float k = gamma[ch] * rsqrtf(var + 1e-5f);
    kv[ch] = k;
    cv[ch] = beta[ch] - mr * k;
}

// ---------------- pooling (batch sorted), fused final BN+ReLU ---------------
__global__ void pool_kernel(const float* __restrict__ aggb, const float* __restrict__ kv,
                            const float* __restrict__ cv, const int* __restrict__ batch,
                            float* __restrict__ pool, int* __restrict__ cnt) {
    int ch = threadIdx.x;
    float k = kv[ch], c = cv[ch];
    int nbase = blockIdx.x * 64;
    float acc = 0.f;
    int mc = 0;
    int curg = batch[nbase];
    for (int r = 0; r < 64; ++r) {
        int n = nbase + r;
        if (n >= NN) break;
        int g = batch[n];
        if (g != curg) {
            atomicAdd(&pool[(size_t)curg * HCC + ch], acc);
            if (ch == 0) atomicAdd(&cnt[curg], mc);
            acc = 0.f; mc = 0; curg = g;
        }
        acc += fmaxf(fmaf(aggb[(size_t)n * HCC + ch], k, c), 0.f);
        mc++;
    }
    atomicAdd(&pool[(size_t)curg * HCC + ch], acc);
    if (ch == 0) atomicAdd(&cnt[curg], mc);
}

__global__ void final_kernel(const float* __restrict__ pool, const int* __restrict__ cnt,
                             float* __restrict__ out) {
    int idx = blockIdx.x * 256 + threadIdx.x;
    int g = idx >> 8;
    float c = fmaxf((float)cnt[g], 1.0f);
    out[idx] = pool[idx] / c;
}

// ---------------- launch ----------------
extern "C" void kernel_launch(void* const* d_in, const int* in_sizes, int n_in,
                              void* d_out, int out_size, void* d_ws, size_t ws_size,
                              hipStream_t stream) {
    const float* x = (const float*)d_in[0];
    const int* edge_index = (const int*)d_in[1];
    const int* srcA = edge_index;
    const int* dstA = edge_index + NE;
    const float* edge_attr = (const float*)d_in[2];
    const int* batch = (const int*)d_in[3];
    const float* W[3]   = {(const float*)d_in[4],  (const float*)d_in[10], (const float*)d_in[16]};
    const float* asc[3] = {(const float*)d_in[5],  (const float*)d_in[11], (const float*)d_in[17]};
    const float* adc[3] = {(const float*)d_in[6],  (const float*)d_in[12], (const float*)d_in[18]};
    const float* gam[3] = {(const float*)d_in[8],  (const float*)d_in[14], (const float*)d_in[20]};
    const float* bet[3] = {(const float*)d_in[9],  (const float*)d_in[15], (const float*)d_in[21]};
    const float* We0 = (const float*)d_in[22];
    const float* att_e0 = (const float*)d_in[23];

    float* wsf = (float*)d_ws;
    unsigned short* hbuf = (unsigned short*)(wsf + O_H);
    float* aggb  = wsf + O_AGG;
    unsigned short* Bt   = (unsigned short*)(wsf + O_BT);
    int*   pos   = (int*)(wsf + O_POS);
    int*   srcP  = (int*)(wsf + O_SRCP);
    float* aeP   = wsf + O_AEP;
    int*   startA= (int*)(wsf + O_START);
    int*   cur   = (int*)(wsf + O_CUR);
    float* asA   = wsf + O_AS;
    float* adA   = wsf + O_AD;
    float* Mb    = wsf + O_M;
    float* kv    = wsf + O_KV;
    float* cv    = wsf + O_CV;
    int*   deg   = (int*)(wsf + O_DEG);
    int*   cnt   = (int*)(wsf + O_CNT);
    int*   ctr   = (int*)(wsf + O_CTR);
    float* slsum = wsf + O_SLS;
    float* sums  = wsf + O_SUM;
    float* ssqs  = wsf + O_SSQ;
    float* pool  = wsf + O_POOL;

    hipMemsetAsync((void*)(wsf + O_ZERO), 0, (O_END - O_ZERO) * sizeof(float), stream);

    // CSR over dst (shared by all layers)
    deg_kernel<<<(ET + 255) / 256, 256, 0, stream>>>(dstA, deg);
    start_kernel<<<(NN + 255) / 256, 256, 0, stream>>>(deg, startA, cur, ctr);
    scatter_kernel<<<(ET + 255) / 256, 256, 0, stream>>>(srcA, dstA, cur, pos, srcP);

    // edge attention logits (layer 0 only), CSR-ordered; self-loop via linearity
    m_kernel<<<1, 64, 0, stream>>>(We0, att_e0, Mb);
    alphae_kernel<<<NE / 256, 256, 0, stream>>>(edge_attr, Mb, pos, aeP, slsum);
    sl_kernel<<<(NN + 255) / 256, 256, 0, stream>>>(slsum, pos, aeP);

    for (int L = 0; L < 3; ++L) {
        int K = (L == 0) ? 128 : 256;
        cvt_w_kernel<<<K, 256, 0, stream>>>(W[L], Bt, K);
        if (L == 0)
            gemm_fused<128, false><<<782, 256, 0, stream>>>(x, Bt, kv, cv, asc[L], adc[L],
                                                            hbuf, asA, adA, NN);
        else
            gemm_fused<256, true><<<782, 256, 0, stream>>>(aggb, Bt, kv, cv, asc[L], adc[L],
                                                           hbuf, asA, adA, NN);
        if (L == 0)
            agg_kernel<true><<<12500, 256, 0, stream>>>(hbuf, asA, adA, aeP, srcP, startA, deg, aggb);
        else
            agg_kernel<false><<<12500, 256, 0, stream>>>(hbuf, asA, adA, aeP, srcP, startA, deg, aggb);
        stats_kernel<<<1024, 256, 0, stream>>>(aggb, sums + L * 256, ssqs + L * 256);
        bnfin_kernel<<<1, 256, 0, stream>>>(sums + L * 256, ssqs + L * 256, gam[L], bet[L], kv, cv);
    }

    pool_kernel<<<782, 256, 0, stream>>>(aggb, kv, cv, batch, pool, cnt);
    final_kernel<<<256, 256, 0, stream>>>(pool, cnt, (float*)d_out);
}